// Round 1
// baseline (327.018 us; speedup 1.0000x reference)
//
#include <hip/hip_runtime.h>

#define DEVI __device__ __forceinline__

typedef __bf16 bf16x8 __attribute__((ext_vector_type(8)));
typedef float f32x4 __attribute__((ext_vector_type(4)));

// ---------- small helpers ----------
DEVI unsigned short f2bf(float f) {
  unsigned u = __builtin_bit_cast(unsigned, f);
  u += 0x7FFFu + ((u >> 16) & 1u);   // RNE
  return (unsigned short)(u >> 16);
}
DEVI float bf2f(unsigned short s) {
  return __builtin_bit_cast(float, ((unsigned)s) << 16);
}
DEVI f32x4 mfma16(bf16x8 a, bf16x8 b, f32x4 c) {
  return __builtin_amdgcn_mfma_f32_16x16x32_bf16(a, b, c, 0, 0, 0);
}
DEVI void gload16(const void* g, void* l) {
  __builtin_amdgcn_global_load_lds(
      (const __attribute__((address_space(1))) void*)g,
      (__attribute__((address_space(3))) void*)l, 16, 0, 0);
}
// LDS fragment read, rows ROWB bytes, XOR-swizzle byte ^= (row&7)<<4
template <int ROWB>
DEVI bf16x8 frag_ld(const char* lds, int row, int kb) {
  int off = row * ROWB + (kb ^ ((row & 7) << 4));
  return __builtin_bit_cast(bf16x8, *(const uint4*)(lds + off));
}

// ---------- fp32 -> bf16 convert ----------
__global__ __launch_bounds__(256) void k_cvt(const float* __restrict__ in,
                                             unsigned short* __restrict__ out, int n4) {
  int i = blockIdx.x * 256 + threadIdx.x;
  int st = gridDim.x * 256;
  for (; i < n4; i += st) {
    float4 f = ((const float4*)in)[i];
    ushort4 o;
    o.x = f2bf(f.x); o.y = f2bf(f.y); o.z = f2bf(f.z); o.w = f2bf(f.w);
    ((ushort4*)out)[i] = o;
  }
}

// ---------- GEMM1: qkv = x * w_qkv^T ; scatter q^T, k^T, v ----------
// x: [16384][768] bf16, w: [2304][768] bf16
// qT,kT: [128 bh][96 d][1024 n] bf16 (raw, unnormalized); vN: [128 bh][1024 n][96 d]
__global__ __launch_bounds__(256) void k_gemm1(const unsigned short* __restrict__ xb,
                                               const unsigned short* __restrict__ wb,
                                               unsigned short* __restrict__ qT,
                                               unsigned short* __restrict__ kT,
                                               unsigned short* __restrict__ vN) {
  __shared__ alignas(16) char lA[16384];  // [128 rows][64 k] bf16, swizzled
  __shared__ alignas(16) char lB[16384];
  const int tid = threadIdx.x, lane = tid & 63, wid = tid >> 6;
  const int wr = wid >> 1, wc = wid & 1;
  const int m0 = blockIdx.y * 128, j0 = blockIdx.x * 128;

  const unsigned short* srcp[8];
  char* dstp[8];
#pragma unroll
  for (int i = 0; i < 8; ++i) {
    int cid = wid * 8 + i;          // 0..31 (16 A chunks, 16 B chunks of 1KB)
    bool isB = cid >= 16;
    int c = cid & 15;
    int p = c * 1024 + lane * 16;   // byte position in 16KB tile
    int r = p >> 7, cb = p & 127;
    int cbs = cb ^ ((r & 7) << 4);  // pre-swizzled source column
    srcp[i] = (isB ? wb + (size_t)(j0 + r) * 768 : xb + (size_t)(m0 + r) * 768) + (cbs >> 1);
    dstp[i] = (isB ? lB : lA) + c * 1024;
  }

  f32x4 acc[4][4];
#pragma unroll
  for (int i = 0; i < 4; ++i)
#pragma unroll
    for (int j = 0; j < 4; ++j)
#pragma unroll
      for (int e = 0; e < 4; ++e) acc[i][j][e] = 0.f;

  for (int k0 = 0; k0 < 768; k0 += 64) {
    __syncthreads();
#pragma unroll
    for (int i = 0; i < 8; ++i) gload16(srcp[i] + k0, dstp[i]);
    __syncthreads();
#pragma unroll
    for (int ks = 0; ks < 2; ++ks) {
      const int kb = ks * 64 + ((lane >> 4) << 4);
      bf16x8 af[4], bfv[4];
#pragma unroll
      for (int mb = 0; mb < 4; ++mb) af[mb] = frag_ld<128>(lA, wr * 64 + mb * 16 + (lane & 15), kb);
#pragma unroll
      for (int nb = 0; nb < 4; ++nb) bfv[nb] = frag_ld<128>(lB, wc * 64 + nb * 16 + (lane & 15), kb);
#pragma unroll
      for (int mb = 0; mb < 4; ++mb)
#pragma unroll
        for (int nb = 0; nb < 4; ++nb) acc[mb][nb] = mfma16(af[mb], bfv[nb], acc[mb][nb]);
    }
  }

  const int s = j0 / 768;  // 0=q 1=k 2=v, constant per block (768 % 128 == 0)
  const int bb = m0 >> 10;
  const int nn0 = (m0 & 1023) + wr * 64 + ((lane >> 4) << 2);
  const int jj0 = (j0 % 768) + wc * 64 + (lane & 15);
#pragma unroll
  for (int mb = 0; mb < 4; ++mb) {
    int n = nn0 + mb * 16;
#pragma unroll
    for (int nb = 0; nb < 4; ++nb) {
      int jj = jj0 + nb * 16;
      int hh = jj / 96, dd = jj % 96;
      if (s == 2) {
        unsigned short* vp = vN + ((size_t)((bb * 8 + hh) * 1024 + n)) * 96 + dd;
#pragma unroll
        for (int rr = 0; rr < 4; ++rr) vp[rr * 96] = f2bf(acc[mb][nb][rr]);
      } else {
        unsigned short* base = (s == 0) ? qT : kT;
        ushort4 pk;
        pk.x = f2bf(acc[mb][nb][0]); pk.y = f2bf(acc[mb][nb][1]);
        pk.z = f2bf(acc[mb][nb][2]); pk.w = f2bf(acc[mb][nb][3]);
        *(ushort4*)(base + ((size_t)((bb * 8 + hh) * 96 + dd)) * 1024 + n) = pk;
      }
    }
  }
}

// ---------- token-dim L2 norms of q,k columns ----------
DEVI float ssq8(uint4 u) {
  unsigned a[4] = {u.x, u.y, u.z, u.w};
  float s = 0.f;
#pragma unroll
  for (int i = 0; i < 4; ++i) {
    float lo = __builtin_bit_cast(float, a[i] << 16);
    float hi = __builtin_bit_cast(float, a[i] & 0xFFFF0000u);
    s += lo * lo + hi * hi;
  }
  return s;
}

__global__ __launch_bounds__(256) void k_norms(const unsigned short* __restrict__ qT,
                                               const unsigned short* __restrict__ kT,
                                               float* __restrict__ nq, float* __restrict__ nk) {
  const int bh = blockIdx.x, tid = threadIdx.x, lane = tid & 63, wid = tid >> 6;
  for (int row = wid; row < 192; row += 4) {
    const unsigned short* src = (row < 96) ? qT + ((size_t)bh * 96 + row) * 1024
                                           : kT + ((size_t)bh * 96 + row - 96) * 1024;
    const uint4* p = (const uint4*)src + lane * 2;
    float s = ssq8(p[0]) + ssq8(p[1]);
#pragma unroll
    for (int off = 32; off; off >>= 1) s += __shfl_xor(s, off, 64);
    if (lane == 0) {
      if (row < 96) nq[bh * 96 + row] = sqrtf(s);
      else          nk[bh * 96 + row - 96] = sqrtf(s);
    }
  }
}

// ---------- A' = q^T k (over N), scale by 1/(|q||k|temp), softmax -> P ----------
__global__ __launch_bounds__(256) void k_attn(const unsigned short* __restrict__ qT,
                                              const unsigned short* __restrict__ kT,
                                              const float* __restrict__ nq,
                                              const float* __restrict__ nk,
                                              const float* __restrict__ temp,
                                              unsigned short* __restrict__ P) {
  __shared__ alignas(16) char lQ[12288];   // [96][64] bf16 swizzled
  __shared__ alignas(16) char lK[12288];
  __shared__ float lA[96 * 96];
  __shared__ float lrq[96], lrk[96];
  const int bh = blockIdx.x, tid = threadIdx.x, lane = tid & 63, wid = tid >> 6;
  if (tid < 96) lrq[tid] = 1.f / fmaxf(nq[bh * 96 + tid], 1e-12f);
  if (tid >= 96 && tid < 192) lrk[tid - 96] = 1.f / fmaxf(nk[bh * 96 + tid - 96], 1e-12f);
  const float invt = 1.f / temp[bh & 7];
  const int wr = wid >> 1, wc = wid & 1;
  const unsigned short* qb = qT + (size_t)bh * 96 * 1024;
  const unsigned short* kb = kT + (size_t)bh * 96 * 1024;

  const unsigned short* srcp[6];
  char* dstp[6];
#pragma unroll
  for (int i = 0; i < 6; ++i) {
    int cid = wid * 6 + i;          // 24 chunks: 12 q + 12 k
    bool isK = cid >= 12;
    int c = isK ? cid - 12 : cid;
    int p = c * 1024 + lane * 16;
    int r = p >> 7, cb = p & 127;
    int cbs = cb ^ ((r & 7) << 4);
    srcp[i] = (isK ? kb : qb) + (size_t)r * 1024 + (cbs >> 1);
    dstp[i] = (isK ? lK : lQ) + c * 1024;
  }

  f32x4 acc[3][3];
#pragma unroll
  for (int i = 0; i < 3; ++i)
#pragma unroll
    for (int j = 0; j < 3; ++j)
#pragma unroll
      for (int e = 0; e < 4; ++e) acc[i][j][e] = 0.f;

  for (int k0 = 0; k0 < 1024; k0 += 64) {
    __syncthreads();
#pragma unroll
    for (int i = 0; i < 6; ++i) gload16(srcp[i] + k0, dstp[i]);
    __syncthreads();
#pragma unroll
    for (int ks = 0; ks < 2; ++ks) {
      const int kb2 = ks * 64 + ((lane >> 4) << 4);
      bf16x8 af[3], bfv[3];
#pragma unroll
      for (int mb = 0; mb < 3; ++mb) af[mb] = frag_ld<128>(lQ, wr * 48 + mb * 16 + (lane & 15), kb2);
#pragma unroll
      for (int nb = 0; nb < 3; ++nb) bfv[nb] = frag_ld<128>(lK, wc * 48 + nb * 16 + (lane & 15), kb2);
#pragma unroll
      for (int mb = 0; mb < 3; ++mb)
#pragma unroll
        for (int nb = 0; nb < 3; ++nb) acc[mb][nb] = mfma16(af[mb], bfv[nb], acc[mb][nb]);
    }
  }

  const int rb = wr * 48 + ((lane >> 4) << 2);
  const int eb = wc * 48 + (lane & 15);
#pragma unroll
  for (int mb = 0; mb < 3; ++mb)
#pragma unroll
    for (int nb = 0; nb < 3; ++nb) {
      int e = eb + nb * 16;
#pragma unroll
      for (int rr = 0; rr < 4; ++rr) {
        int d = rb + mb * 16 + rr;
        lA[d * 96 + e] = acc[mb][nb][rr] * lrq[d] * lrk[e] * invt;
      }
    }
  __syncthreads();
  for (int d = wid; d < 96; d += 4) {
    float v0 = lA[d * 96 + lane];
    float v1 = (lane < 32) ? lA[d * 96 + 64 + lane] : -3.0e38f;
    float mx = fmaxf(v0, v1);
#pragma unroll
    for (int off = 32; off; off >>= 1) mx = fmaxf(mx, __shfl_xor(mx, off, 64));
    float p0 = __expf(v0 - mx);
    float p1 = (lane < 32) ? __expf(v1 - mx) : 0.f;
    float ssum = p0 + p1;
#pragma unroll
    for (int off = 32; off; off >>= 1) ssum += __shfl_xor(ssum, off, 64);
    float rs = 1.f / ssum;
    unsigned short* prow = P + ((size_t)bh * 96 + d) * 96;
    prow[lane] = f2bf(p0 * rs);
    if (lane < 32) prow[64 + lane] = f2bf(p1 * rs);
  }
}

// ---------- x_xca = v @ P^T  -> xca [16384][768] bf16 ----------
__global__ __launch_bounds__(256) void k_pv(const unsigned short* __restrict__ vN,
                                            const unsigned short* __restrict__ P,
                                            unsigned short* __restrict__ xca) {
  __shared__ alignas(16) char lV[128 * 256];  // rows padded to 128 bf16, swizzled
  __shared__ alignas(16) char lP[96 * 256];
  const int bh = blockIdx.x, mt = blockIdx.y;
  const int n0 = mt * 128;
  const int bb = bh >> 3, hh = bh & 7;
  const int tid = threadIdx.x, lane = tid & 63, wid = tid >> 6;
  const int wr = wid >> 1, wc = wid & 1;

  const unsigned short* vb = vN + ((size_t)bh * 1024 + n0) * 96;
  for (int idx = tid; idx < 1536; idx += 256) {  // 128 rows * 12 chunks
    int r = idx / 12, ch = idx % 12;
    uint4 u = *(const uint4*)(vb + (size_t)r * 96 + ch * 8);
    *(uint4*)(lV + r * 256 + ((ch * 16) ^ ((r & 7) << 4))) = u;
  }
  const unsigned short* pb = P + (size_t)bh * 96 * 96;
  for (int idx = tid; idx < 1152; idx += 256) {  // 96 rows * 12 chunks
    int r = idx / 12, ch = idx % 12;
    uint4 u = *(const uint4*)(pb + r * 96 + ch * 8);
    *(uint4*)(lP + r * 256 + ((ch * 16) ^ ((r & 7) << 4))) = u;
  }
  __syncthreads();

  f32x4 acc[4][3];
#pragma unroll
  for (int i = 0; i < 4; ++i)
#pragma unroll
    for (int j = 0; j < 3; ++j)
#pragma unroll
      for (int e = 0; e < 4; ++e) acc[i][j][e] = 0.f;

#pragma unroll
  for (int ks = 0; ks < 3; ++ks) {
    const int kb = ks * 64 + ((lane >> 4) << 4);
    bf16x8 af[4], bfv[3];
#pragma unroll
    for (int mb = 0; mb < 4; ++mb) af[mb] = frag_ld<256>(lV, wr * 64 + mb * 16 + (lane & 15), kb);
#pragma unroll
    for (int nb = 0; nb < 3; ++nb) bfv[nb] = frag_ld<256>(lP, wc * 48 + nb * 16 + (lane & 15), kb);
#pragma unroll
    for (int mb = 0; mb < 4; ++mb)
#pragma unroll
      for (int nb = 0; nb < 3; ++nb) acc[mb][nb] = mfma16(af[mb], bfv[nb], acc[mb][nb]);
  }

  const int nb0 = n0 + wr * 64 + ((lane >> 4) << 2);
  const int db0 = wc * 48 + (lane & 15);
#pragma unroll
  for (int mb = 0; mb < 4; ++mb)
#pragma unroll
    for (int nb = 0; nb < 3; ++nb) {
      int dd = db0 + nb * 16;
#pragma unroll
      for (int rr = 0; rr < 4; ++rr) {
        int n = nb0 + mb * 16 + rr;
        xca[((size_t)(bb * 1024 + n)) * 768 + hh * 96 + dd] = f2bf(acc[mb][nb][rr]);
      }
    }
}

// ---------- GEMM2: yp = xca * w_proj^T (fp32 out) ----------
__global__ __launch_bounds__(256) void k_gemm2(const unsigned short* __restrict__ xca,
                                               const unsigned short* __restrict__ wb,
                                               float* __restrict__ yp) {
  __shared__ alignas(16) char lA[16384];
  __shared__ alignas(16) char lB[16384];
  const int tid = threadIdx.x, lane = tid & 63, wid = tid >> 6;
  const int wr = wid >> 1, wc = wid & 1;
  const int m0 = blockIdx.y * 128, j0 = blockIdx.x * 128;

  const unsigned short* srcp[8];
  char* dstp[8];
#pragma unroll
  for (int i = 0; i < 8; ++i) {
    int cid = wid * 8 + i;
    bool isB = cid >= 16;
    int c = cid & 15;
    int p = c * 1024 + lane * 16;
    int r = p >> 7, cb = p & 127;
    int cbs = cb ^ ((r & 7) << 4);
    srcp[i] = (isB ? wb + (size_t)(j0 + r) * 768 : xca + (size_t)(m0 + r) * 768) + (cbs >> 1);
    dstp[i] = (isB ? lB : lA) + c * 1024;
  }

  f32x4 acc[4][4];
#pragma unroll
  for (int i = 0; i < 4; ++i)
#pragma unroll
    for (int j = 0; j < 4; ++j)
#pragma unroll
      for (int e = 0; e < 4; ++e) acc[i][j][e] = 0.f;

  for (int k0 = 0; k0 < 768; k0 += 64) {
    __syncthreads();
#pragma unroll
    for (int i = 0; i < 8; ++i) gload16(srcp[i] + k0, dstp[i]);
    __syncthreads();
#pragma unroll
    for (int ks = 0; ks < 2; ++ks) {
      const int kb = ks * 64 + ((lane >> 4) << 4);
      bf16x8 af[4], bfv[4];
#pragma unroll
      for (int mb = 0; mb < 4; ++mb) af[mb] = frag_ld<128>(lA, wr * 64 + mb * 16 + (lane & 15), kb);
#pragma unroll
      for (int nb = 0; nb < 4; ++nb) bfv[nb] = frag_ld<128>(lB, wc * 64 + nb * 16 + (lane & 15), kb);
#pragma unroll
      for (int mb = 0; mb < 4; ++mb)
#pragma unroll
        for (int nb = 0; nb < 4; ++nb) acc[mb][nb] = mfma16(af[mb], bfv[nb], acc[mb][nb]);
    }
  }

  const int row0 = m0 + wr * 64 + ((lane >> 4) << 2);
  const int col0 = j0 + wc * 64 + (lane & 15);
#pragma unroll
  for (int mb = 0; mb < 4; ++mb)
#pragma unroll
    for (int nb = 0; nb < 4; ++nb)
#pragma unroll
      for (int rr = 0; rr < 4; ++rr)
        yp[(size_t)(row0 + mb * 16 + rr) * 768 + col0 + nb * 16] = acc[mb][nb][rr];
}

// ---------- final: y = yp + 0.1*dwconv3x3(x); LayerNorm(y)*gamma+beta ----------
__global__ __launch_bounds__(256) void k_final(const float* __restrict__ yp,
                                               const float* __restrict__ x,
                                               const float* __restrict__ cw,
                                               const float* __restrict__ gamma,
                                               const float* __restrict__ beta,
                                               float* __restrict__ out) {
  const int m = blockIdx.x, tid = threadIdx.x;
  const int bb = m >> 10, n = m & 1023, yy = n >> 5, xx = n & 31;
  const float* xb = x + (size_t)bb * 1024 * 768;
  float yv[3];
#pragma unroll
  for (int q = 0; q < 3; ++q) {
    int c = tid + q * 256;
    float a = 0.f;
#pragma unroll
    for (int dy = -1; dy <= 1; ++dy) {
      int ny = yy + dy;
      if ((unsigned)ny < 32u) {
#pragma unroll
        for (int dx = -1; dx <= 1; ++dx) {
          int nx = xx + dx;
          if ((unsigned)nx < 32u)
            a += cw[c * 9 + (dy + 1) * 3 + (dx + 1)] * xb[(size_t)(ny * 32 + nx) * 768 + c];
        }
      }
    }
    yv[q] = yp[(size_t)m * 768 + c] + 0.1f * a;
  }
  float s1 = yv[0] + yv[1] + yv[2];
  float s2 = yv[0] * yv[0] + yv[1] * yv[1] + yv[2] * yv[2];
#pragma unroll
  for (int off = 32; off; off >>= 1) {
    s1 += __shfl_xor(s1, off, 64);
    s2 += __shfl_xor(s2, off, 64);
  }
  __shared__ float ls1[4], ls2[4];
  const int wid = tid >> 6, lane = tid & 63;
  if (lane == 0) { ls1[wid] = s1; ls2[wid] = s2; }
  __syncthreads();
  s1 = ls1[0] + ls1[1] + ls1[2] + ls1[3];
  s2 = ls2[0] + ls2[1] + ls2[2] + ls2[3];
  const float mu = s1 * (1.f / 768.f);
  const float var = s2 * (1.f / 768.f) - mu * mu;
  const float rs = rsqrtf(var + 1e-5f);
#pragma unroll
  for (int q = 0; q < 3; ++q) {
    int c = tid + q * 256;
    out[(size_t)m * 768 + c] = (yv[q] - mu) * rs * gamma[c] + beta[c];
  }
}

// ---------- host ----------
extern "C" void kernel_launch(void* const* d_in, const int* in_sizes, int n_in,
                              void* d_out, int out_size, void* d_ws, size_t ws_size,
                              hipStream_t stream) {
  const float* x     = (const float*)d_in[0];
  const float* wqkv  = (const float*)d_in[1];
  const float* wproj = (const float*)d_in[2];
  const float* temp  = (const float*)d_in[3];
  const float* cw    = (const float*)d_in[4];
  const float* gamma = (const float*)d_in[5];
  const float* beta  = (const float*)d_in[6];
  float* out = (float*)d_out;
  char* ws = (char*)d_ws;

  // workspace layout (all offsets 256B-aligned); total ~103 MiB
  unsigned short* xb  = (unsigned short*)(ws);               // 25165824 B (reused as xca)
  unsigned short* wqb = (unsigned short*)(ws + 25165824);    // 3538944
  unsigned short* wpb = (unsigned short*)(ws + 28704768);    // 1179648
  unsigned short* qT  = (unsigned short*)(ws + 29884416);    // 25165824
  unsigned short* kT  = (unsigned short*)(ws + 55050240);    // 25165824
  unsigned short* vN  = (unsigned short*)(ws + 80216064);    // 25165824
  float* nq           = (float*)(ws + 105381888);            // 49152
  float* nk           = (float*)(ws + 105431040);            // 49152
  unsigned short* P   = (unsigned short*)(ws + 105480192);   // 2359296
  float* yp           = (float*)(ws + 29884416);             // aliases qT+kT (dead by then)
  unsigned short* xca = xb;                                  // aliases xb (dead by then)

  k_cvt<<<dim3(2048), dim3(256), 0, stream>>>(x, xb, 16384 * 768 / 4);
  k_cvt<<<dim3(1728), dim3(256), 0, stream>>>(wqkv, wqb, 2304 * 768 / 4);
  k_cvt<<<dim3(576), dim3(256), 0, stream>>>(wproj, wpb, 768 * 768 / 4);
  k_gemm1<<<dim3(18, 128), dim3(256), 0, stream>>>(xb, wqb, qT, kT, vN);
  k_norms<<<dim3(128), dim3(256), 0, stream>>>(qT, kT, nq, nk);
  k_attn<<<dim3(128), dim3(256), 0, stream>>>(qT, kT, nq, nk, temp, P);
  k_pv<<<dim3(128, 8), dim3(256), 0, stream>>>(vN, P, xca);
  k_gemm2<<<dim3(6, 128), dim3(256), 0, stream>>>(xca, wpb, yp);
  k_final<<<dim3(16384), dim3(256), 0, stream>>>(yp, x, cw, gamma, beta, out);
}

// Round 2
// 262.448 us; speedup vs baseline: 1.2460x; 1.2460x over previous
//
#include <hip/hip_runtime.h>

#define DEVI __device__ __forceinline__

typedef __bf16 bf16x8 __attribute__((ext_vector_type(8)));
typedef float f32x4 __attribute__((ext_vector_type(4)));

// ---------- small helpers ----------
DEVI unsigned short f2bf(float f) {
  unsigned u = __builtin_bit_cast(unsigned, f);
  u += 0x7FFFu + ((u >> 16) & 1u);   // RNE
  return (unsigned short)(u >> 16);
}
DEVI float bf2f(unsigned short s) {
  return __builtin_bit_cast(float, ((unsigned)s) << 16);
}
DEVI f32x4 mfma16(bf16x8 a, bf16x8 b, f32x4 c) {
  return __builtin_amdgcn_mfma_f32_16x16x32_bf16(a, b, c, 0, 0, 0);
}
DEVI void gload16(const void* g, void* l) {
  __builtin_amdgcn_global_load_lds(
      (const __attribute__((address_space(1))) void*)g,
      (__attribute__((address_space(3))) void*)l, 16, 0, 0);
}
// LDS fragment read, rows ROWB bytes, XOR-swizzle byte ^= (row&7)<<4
template <int ROWB>
DEVI bf16x8 frag_ld(const char* lds, int row, int kb) {
  int off = row * ROWB + (kb ^ ((row & 7) << 4));
  return __builtin_bit_cast(bf16x8, *(const uint4*)(lds + off));
}

// ---------- fp32 -> bf16 convert ----------
__global__ __launch_bounds__(256) void k_cvt(const float* __restrict__ in,
                                             unsigned short* __restrict__ out, int n4) {
  int i = blockIdx.x * 256 + threadIdx.x;
  int st = gridDim.x * 256;
  for (; i < n4; i += st) {
    float4 f = ((const float4*)in)[i];
    ushort4 o;
    o.x = f2bf(f.x); o.y = f2bf(f.y); o.z = f2bf(f.z); o.w = f2bf(f.w);
    ((ushort4*)out)[i] = o;
  }
}

// ---------- GEMM1: qkv = x * w_qkv^T ; scatter q^T, k^T, v ----------
// x: [16384][768] bf16, w: [2304][768] bf16
// qT,kT: [128 bh][96 d][1024 n] bf16 (raw, unnormalized); vN: [128 bh][1024 n][96 d]
__global__ __launch_bounds__(256) void k_gemm1(const unsigned short* __restrict__ xb,
                                               const unsigned short* __restrict__ wb,
                                               unsigned short* __restrict__ qT,
                                               unsigned short* __restrict__ kT,
                                               unsigned short* __restrict__ vN) {
  __shared__ alignas(16) char lA[16384];  // [128 rows][64 k] bf16, swizzled
  __shared__ alignas(16) char lB[16384];
  const int tid = threadIdx.x, lane = tid & 63, wid = tid >> 6;
  const int wr = wid >> 1, wc = wid & 1;
  const int m0 = blockIdx.y * 128, j0 = blockIdx.x * 128;

  const unsigned short* srcp[8];
  char* dstp[8];
#pragma unroll
  for (int i = 0; i < 8; ++i) {
    int cid = wid * 8 + i;          // 0..31 (16 A chunks, 16 B chunks of 1KB)
    bool isB = cid >= 16;
    int c = cid & 15;
    int p = c * 1024 + lane * 16;   // byte position in 16KB tile
    int r = p >> 7, cb = p & 127;
    int cbs = cb ^ ((r & 7) << 4);  // pre-swizzled source column
    srcp[i] = (isB ? wb + (size_t)(j0 + r) * 768 : xb + (size_t)(m0 + r) * 768) + (cbs >> 1);
    dstp[i] = (isB ? lB : lA) + c * 1024;
  }

  f32x4 acc[4][4];
#pragma unroll
  for (int i = 0; i < 4; ++i)
#pragma unroll
    for (int j = 0; j < 4; ++j)
#pragma unroll
      for (int e = 0; e < 4; ++e) acc[i][j][e] = 0.f;

  for (int k0 = 0; k0 < 768; k0 += 64) {
    __syncthreads();
#pragma unroll
    for (int i = 0; i < 8; ++i) gload16(srcp[i] + k0, dstp[i]);
    __syncthreads();
#pragma unroll
    for (int ks = 0; ks < 2; ++ks) {
      const int kb = ks * 64 + ((lane >> 4) << 4);
      bf16x8 af[4], bfv[4];
#pragma unroll
      for (int mb = 0; mb < 4; ++mb) af[mb] = frag_ld<128>(lA, wr * 64 + mb * 16 + (lane & 15), kb);
#pragma unroll
      for (int nb = 0; nb < 4; ++nb) bfv[nb] = frag_ld<128>(lB, wc * 64 + nb * 16 + (lane & 15), kb);
#pragma unroll
      for (int mb = 0; mb < 4; ++mb)
#pragma unroll
        for (int nb = 0; nb < 4; ++nb) acc[mb][nb] = mfma16(af[mb], bfv[nb], acc[mb][nb]);
    }
  }

  const int s = j0 / 768;  // 0=q 1=k 2=v, constant per block (768 % 128 == 0)
  const int bb = m0 >> 10;
  const int nn0 = (m0 & 1023) + wr * 64 + ((lane >> 4) << 2);
  const int jj0 = (j0 % 768) + wc * 64 + (lane & 15);
#pragma unroll
  for (int mb = 0; mb < 4; ++mb) {
    int n = nn0 + mb * 16;
#pragma unroll
    for (int nb = 0; nb < 4; ++nb) {
      int jj = jj0 + nb * 16;
      int hh = jj / 96, dd = jj % 96;
      if (s == 2) {
        unsigned short* vp = vN + ((size_t)((bb * 8 + hh) * 1024 + n)) * 96 + dd;
#pragma unroll
        for (int rr = 0; rr < 4; ++rr) vp[rr * 96] = f2bf(acc[mb][nb][rr]);
      } else {
        unsigned short* base = (s == 0) ? qT : kT;
        ushort4 pk;
        pk.x = f2bf(acc[mb][nb][0]); pk.y = f2bf(acc[mb][nb][1]);
        pk.z = f2bf(acc[mb][nb][2]); pk.w = f2bf(acc[mb][nb][3]);
        *(ushort4*)(base + ((size_t)((bb * 8 + hh) * 96 + dd)) * 1024 + n) = pk;
      }
    }
  }
}

// ---------- token-dim L2 norms of q,k columns ----------
DEVI float ssq8(uint4 u) {
  unsigned a[4] = {u.x, u.y, u.z, u.w};
  float s = 0.f;
#pragma unroll
  for (int i = 0; i < 4; ++i) {
    float lo = __builtin_bit_cast(float, a[i] << 16);
    float hi = __builtin_bit_cast(float, a[i] & 0xFFFF0000u);
    s += lo * lo + hi * hi;
  }
  return s;
}

__global__ __launch_bounds__(256) void k_norms(const unsigned short* __restrict__ qT,
                                               const unsigned short* __restrict__ kT,
                                               float* __restrict__ nq, float* __restrict__ nk) {
  const int bh = blockIdx.x, tid = threadIdx.x, lane = tid & 63, wid = tid >> 6;
  for (int row = wid; row < 192; row += 4) {
    const unsigned short* src = (row < 96) ? qT + ((size_t)bh * 96 + row) * 1024
                                           : kT + ((size_t)bh * 96 + row - 96) * 1024;
    const uint4* p = (const uint4*)src + lane * 2;
    float s = ssq8(p[0]) + ssq8(p[1]);
#pragma unroll
    for (int off = 32; off; off >>= 1) s += __shfl_xor(s, off, 64);
    if (lane == 0) {
      if (row < 96) nq[bh * 96 + row] = sqrtf(s);
      else          nk[bh * 96 + row - 96] = sqrtf(s);
    }
  }
}

// ---------- A' = q^T k (over N), scale by 1/(|q||k|temp), softmax -> P ----------
__global__ __launch_bounds__(256) void k_attn(const unsigned short* __restrict__ qT,
                                              const unsigned short* __restrict__ kT,
                                              const float* __restrict__ nq,
                                              const float* __restrict__ nk,
                                              const float* __restrict__ temp,
                                              unsigned short* __restrict__ P) {
  __shared__ alignas(16) char lQ[12288];   // [96][64] bf16 swizzled
  __shared__ alignas(16) char lK[12288];
  __shared__ float lA[96 * 96];
  __shared__ float lrq[96], lrk[96];
  const int bh = blockIdx.x, tid = threadIdx.x, lane = tid & 63, wid = tid >> 6;
  if (tid < 96) lrq[tid] = 1.f / fmaxf(nq[bh * 96 + tid], 1e-12f);
  if (tid >= 96 && tid < 192) lrk[tid - 96] = 1.f / fmaxf(nk[bh * 96 + tid - 96], 1e-12f);
  const float invt = 1.f / temp[bh & 7];
  const int wr = wid >> 1, wc = wid & 1;
  const unsigned short* qb = qT + (size_t)bh * 96 * 1024;
  const unsigned short* kb = kT + (size_t)bh * 96 * 1024;

  const unsigned short* srcp[6];
  char* dstp[6];
#pragma unroll
  for (int i = 0; i < 6; ++i) {
    int cid = wid * 6 + i;          // 24 chunks: 12 q + 12 k
    bool isK = cid >= 12;
    int c = isK ? cid - 12 : cid;
    int p = c * 1024 + lane * 16;
    int r = p >> 7, cb = p & 127;
    int cbs = cb ^ ((r & 7) << 4);
    srcp[i] = (isK ? kb : qb) + (size_t)r * 1024 + (cbs >> 1);
    dstp[i] = (isK ? lK : lQ) + c * 1024;
  }

  f32x4 acc[3][3];
#pragma unroll
  for (int i = 0; i < 3; ++i)
#pragma unroll
    for (int j = 0; j < 3; ++j)
#pragma unroll
      for (int e = 0; e < 4; ++e) acc[i][j][e] = 0.f;

  for (int k0 = 0; k0 < 1024; k0 += 64) {
    __syncthreads();
#pragma unroll
    for (int i = 0; i < 6; ++i) gload16(srcp[i] + k0, dstp[i]);
    __syncthreads();
#pragma unroll
    for (int ks = 0; ks < 2; ++ks) {
      const int kb2 = ks * 64 + ((lane >> 4) << 4);
      bf16x8 af[3], bfv[3];
#pragma unroll
      for (int mb = 0; mb < 3; ++mb) af[mb] = frag_ld<128>(lQ, wr * 48 + mb * 16 + (lane & 15), kb2);
#pragma unroll
      for (int nb = 0; nb < 3; ++nb) bfv[nb] = frag_ld<128>(lK, wc * 48 + nb * 16 + (lane & 15), kb2);
#pragma unroll
      for (int mb = 0; mb < 3; ++mb)
#pragma unroll
        for (int nb = 0; nb < 3; ++nb) acc[mb][nb] = mfma16(af[mb], bfv[nb], acc[mb][nb]);
    }
  }

  const int rb = wr * 48 + ((lane >> 4) << 2);
  const int eb = wc * 48 + (lane & 15);
#pragma unroll
  for (int mb = 0; mb < 3; ++mb)
#pragma unroll
    for (int nb = 0; nb < 3; ++nb) {
      int e = eb + nb * 16;
#pragma unroll
      for (int rr = 0; rr < 4; ++rr) {
        int d = rb + mb * 16 + rr;
        lA[d * 96 + e] = acc[mb][nb][rr] * lrq[d] * lrk[e] * invt;
      }
    }
  __syncthreads();
  for (int d = wid; d < 96; d += 4) {
    float v0 = lA[d * 96 + lane];
    float v1 = (lane < 32) ? lA[d * 96 + 64 + lane] : -3.0e38f;
    float mx = fmaxf(v0, v1);
#pragma unroll
    for (int off = 32; off; off >>= 1) mx = fmaxf(mx, __shfl_xor(mx, off, 64));
    float p0 = __expf(v0 - mx);
    float p1 = (lane < 32) ? __expf(v1 - mx) : 0.f;
    float ssum = p0 + p1;
#pragma unroll
    for (int off = 32; off; off >>= 1) ssum += __shfl_xor(ssum, off, 64);
    float rs = 1.f / ssum;
    unsigned short* prow = P + ((size_t)bh * 96 + d) * 96;
    prow[lane] = f2bf(p0 * rs);
    if (lane < 32) prow[64 + lane] = f2bf(p1 * rs);
  }
}

// ---------- x_xca = v @ P^T  -> xca [16384][768] bf16 ----------
__global__ __launch_bounds__(256) void k_pv(const unsigned short* __restrict__ vN,
                                            const unsigned short* __restrict__ P,
                                            unsigned short* __restrict__ xca) {
  __shared__ alignas(16) char lV[128 * 256];  // rows padded to 128 bf16, swizzled
  __shared__ alignas(16) char lP[96 * 256];
  const int bh = blockIdx.x, mt = blockIdx.y;
  const int n0 = mt * 128;
  const int bb = bh >> 3, hh = bh & 7;
  const int tid = threadIdx.x, lane = tid & 63, wid = tid >> 6;
  const int wr = wid >> 1, wc = wid & 1;

  const unsigned short* vb = vN + ((size_t)bh * 1024 + n0) * 96;
  for (int idx = tid; idx < 1536; idx += 256) {  // 128 rows * 12 chunks
    int r = idx / 12, ch = idx % 12;
    uint4 u = *(const uint4*)(vb + (size_t)r * 96 + ch * 8);
    *(uint4*)(lV + r * 256 + ((ch * 16) ^ ((r & 7) << 4))) = u;
  }
  const unsigned short* pb = P + (size_t)bh * 96 * 96;
  for (int idx = tid; idx < 1152; idx += 256) {  // 96 rows * 12 chunks
    int r = idx / 12, ch = idx % 12;
    uint4 u = *(const uint4*)(pb + r * 96 + ch * 8);
    *(uint4*)(lP + r * 256 + ((ch * 16) ^ ((r & 7) << 4))) = u;
  }
  __syncthreads();

  f32x4 acc[4][3];
#pragma unroll
  for (int i = 0; i < 4; ++i)
#pragma unroll
    for (int j = 0; j < 3; ++j)
#pragma unroll
      for (int e = 0; e < 4; ++e) acc[i][j][e] = 0.f;

#pragma unroll
  for (int ks = 0; ks < 3; ++ks) {
    const int kb = ks * 64 + ((lane >> 4) << 4);
    bf16x8 af[4], bfv[3];
#pragma unroll
    for (int mb = 0; mb < 4; ++mb) af[mb] = frag_ld<256>(lV, wr * 64 + mb * 16 + (lane & 15), kb);
#pragma unroll
    for (int nb = 0; nb < 3; ++nb) bfv[nb] = frag_ld<256>(lP, wc * 48 + nb * 16 + (lane & 15), kb);
#pragma unroll
    for (int mb = 0; mb < 4; ++mb)
#pragma unroll
      for (int nb = 0; nb < 3; ++nb) acc[mb][nb] = mfma16(af[mb], bfv[nb], acc[mb][nb]);
  }

  const int nb0 = n0 + wr * 64 + ((lane >> 4) << 2);
  const int db0 = wc * 48 + (lane & 15);
#pragma unroll
  for (int mb = 0; mb < 4; ++mb)
#pragma unroll
    for (int nb = 0; nb < 3; ++nb) {
      int dd = db0 + nb * 16;
#pragma unroll
      for (int rr = 0; rr < 4; ++rr) {
        int n = nb0 + mb * 16 + rr;
        xca[((size_t)(bb * 1024 + n)) * 768 + hh * 96 + dd] = f2bf(acc[mb][nb][rr]);
      }
    }
}

// ---------- GEMM2: yp = xca * w_proj^T (fp32 out) ----------
__global__ __launch_bounds__(256) void k_gemm2(const unsigned short* __restrict__ xca,
                                               const unsigned short* __restrict__ wb,
                                               float* __restrict__ yp) {
  __shared__ alignas(16) char lA[16384];
  __shared__ alignas(16) char lB[16384];
  const int tid = threadIdx.x, lane = tid & 63, wid = tid >> 6;
  const int wr = wid >> 1, wc = wid & 1;
  const int m0 = blockIdx.y * 128, j0 = blockIdx.x * 128;

  const unsigned short* srcp[8];
  char* dstp[8];
#pragma unroll
  for (int i = 0; i < 8; ++i) {
    int cid = wid * 8 + i;
    bool isB = cid >= 16;
    int c = cid & 15;
    int p = c * 1024 + lane * 16;
    int r = p >> 7, cb = p & 127;
    int cbs = cb ^ ((r & 7) << 4);
    srcp[i] = (isB ? wb + (size_t)(j0 + r) * 768 : xca + (size_t)(m0 + r) * 768) + (cbs >> 1);
    dstp[i] = (isB ? lB : lA) + c * 1024;
  }

  f32x4 acc[4][4];
#pragma unroll
  for (int i = 0; i < 4; ++i)
#pragma unroll
    for (int j = 0; j < 4; ++j)
#pragma unroll
      for (int e = 0; e < 4; ++e) acc[i][j][e] = 0.f;

  for (int k0 = 0; k0 < 768; k0 += 64) {
    __syncthreads();
#pragma unroll
    for (int i = 0; i < 8; ++i) gload16(srcp[i] + k0, dstp[i]);
    __syncthreads();
#pragma unroll
    for (int ks = 0; ks < 2; ++ks) {
      const int kb = ks * 64 + ((lane >> 4) << 4);
      bf16x8 af[4], bfv[4];
#pragma unroll
      for (int mb = 0; mb < 4; ++mb) af[mb] = frag_ld<128>(lA, wr * 64 + mb * 16 + (lane & 15), kb);
#pragma unroll
      for (int nb = 0; nb < 4; ++nb) bfv[nb] = frag_ld<128>(lB, wc * 64 + nb * 16 + (lane & 15), kb);
#pragma unroll
      for (int mb = 0; mb < 4; ++mb)
#pragma unroll
        for (int nb = 0; nb < 4; ++nb) acc[mb][nb] = mfma16(af[mb], bfv[nb], acc[mb][nb]);
    }
  }

  const int row0 = m0 + wr * 64 + ((lane >> 4) << 2);
  const int col0 = j0 + wc * 64 + (lane & 15);
#pragma unroll
  for (int mb = 0; mb < 4; ++mb)
#pragma unroll
    for (int nb = 0; nb < 4; ++nb)
#pragma unroll
      for (int rr = 0; rr < 4; ++rr)
        yp[(size_t)(row0 + mb * 16 + rr) * 768 + col0 + nb * 16] = acc[mb][nb][rr];
}

// ---------- final: y = yp + 0.1*dwconv3x3(x); LayerNorm(y)*gamma+beta ----------
// wave-per-token, float4-vectorized: each lane owns 12 channels (3 groups x 4).
__global__ __launch_bounds__(256) void k_final(const float* __restrict__ yp,
                                               const float* __restrict__ x,
                                               const float* __restrict__ cw,
                                               const float* __restrict__ gamma,
                                               const float* __restrict__ beta,
                                               float* __restrict__ out) {
  const int wid = threadIdx.x >> 6, lane = threadIdx.x & 63;
  const int m = blockIdx.x * 4 + wid;           // token id
  const int bb = m >> 10, n = m & 1023, yy = n >> 5, xx = n & 31;
  const float* xb = x + (size_t)bb * 1024 * 768;

  float yv[3][4];
#pragma unroll
  for (int g = 0; g < 3; ++g) {
    const int c = g * 256 + lane * 4;
    // conv weights for channels c..c+3: 36 consecutive floats, 16B-aligned
    float w36[36];
    const float4* wp = (const float4*)(cw + (size_t)c * 9);
#pragma unroll
    for (int i = 0; i < 9; ++i) *(float4*)(w36 + i * 4) = wp[i];

    float a0 = 0.f, a1 = 0.f, a2 = 0.f, a3 = 0.f;
#pragma unroll
    for (int dy = -1; dy <= 1; ++dy) {
      int ny = yy + dy;
      if ((unsigned)ny < 32u) {
#pragma unroll
        for (int dx = -1; dx <= 1; ++dx) {
          int nx = xx + dx;
          if ((unsigned)nx < 32u) {
            float4 v = *(const float4*)(xb + (size_t)(ny * 32 + nx) * 768 + c);
            const int j = (dy + 1) * 3 + (dx + 1);
            a0 += w36[0 * 9 + j] * v.x;
            a1 += w36[1 * 9 + j] * v.y;
            a2 += w36[2 * 9 + j] * v.z;
            a3 += w36[3 * 9 + j] * v.w;
          }
        }
      }
    }
    float4 f = *(const float4*)(yp + (size_t)m * 768 + c);
    yv[g][0] = f.x + 0.1f * a0;
    yv[g][1] = f.y + 0.1f * a1;
    yv[g][2] = f.z + 0.1f * a2;
    yv[g][3] = f.w + 0.1f * a3;
  }

  float s1 = 0.f, s2 = 0.f;
#pragma unroll
  for (int g = 0; g < 3; ++g)
#pragma unroll
    for (int e = 0; e < 4; ++e) { s1 += yv[g][e]; s2 += yv[g][e] * yv[g][e]; }
#pragma unroll
  for (int off = 32; off; off >>= 1) {
    s1 += __shfl_xor(s1, off, 64);
    s2 += __shfl_xor(s2, off, 64);
  }
  const float mu = s1 * (1.f / 768.f);
  const float var = s2 * (1.f / 768.f) - mu * mu;
  const float rs = rsqrtf(var + 1e-5f);

#pragma unroll
  for (int g = 0; g < 3; ++g) {
    const int c = g * 256 + lane * 4;
    float4 gm = *(const float4*)(gamma + c);
    float4 bt = *(const float4*)(beta + c);
    float4 o;
    o.x = (yv[g][0] - mu) * rs * gm.x + bt.x;
    o.y = (yv[g][1] - mu) * rs * gm.y + bt.y;
    o.z = (yv[g][2] - mu) * rs * gm.z + bt.z;
    o.w = (yv[g][3] - mu) * rs * gm.w + bt.w;
    *(float4*)(out + (size_t)m * 768 + c) = o;
  }
}

// ---------- host ----------
extern "C" void kernel_launch(void* const* d_in, const int* in_sizes, int n_in,
                              void* d_out, int out_size, void* d_ws, size_t ws_size,
                              hipStream_t stream) {
  const float* x     = (const float*)d_in[0];
  const float* wqkv  = (const float*)d_in[1];
  const float* wproj = (const float*)d_in[2];
  const float* temp  = (const float*)d_in[3];
  const float* cw    = (const float*)d_in[4];
  const float* gamma = (const float*)d_in[5];
  const float* beta  = (const float*)d_in[6];
  float* out = (float*)d_out;
  char* ws = (char*)d_ws;

  // workspace layout (all offsets 256B-aligned); total ~103 MiB
  unsigned short* xb  = (unsigned short*)(ws);               // 25165824 B (reused as xca)
  unsigned short* wqb = (unsigned short*)(ws + 25165824);    // 3538944
  unsigned short* wpb = (unsigned short*)(ws + 28704768);    // 1179648
  unsigned short* qT  = (unsigned short*)(ws + 29884416);    // 25165824
  unsigned short* kT  = (unsigned short*)(ws + 55050240);    // 25165824
  unsigned short* vN  = (unsigned short*)(ws + 80216064);    // 25165824
  float* nq           = (float*)(ws + 105381888);            // 49152
  float* nk           = (float*)(ws + 105431040);            // 49152
  unsigned short* P   = (unsigned short*)(ws + 105480192);   // 2359296
  float* yp           = (float*)(ws + 29884416);             // aliases qT+kT (dead by then)
  unsigned short* xca = xb;                                  // aliases xb (dead by then)

  k_cvt<<<dim3(2048), dim3(256), 0, stream>>>(x, xb, 16384 * 768 / 4);
  k_cvt<<<dim3(1728), dim3(256), 0, stream>>>(wqkv, wqb, 2304 * 768 / 4);
  k_cvt<<<dim3(576), dim3(256), 0, stream>>>(wproj, wpb, 768 * 768 / 4);
  k_gemm1<<<dim3(18, 128), dim3(256), 0, stream>>>(xb, wqb, qT, kT, vN);
  k_norms<<<dim3(128), dim3(256), 0, stream>>>(qT, kT, nq, nk);
  k_attn<<<dim3(128), dim3(256), 0, stream>>>(qT, kT, nq, nk, temp, P);
  k_pv<<<dim3(128, 8), dim3(256), 0, stream>>>(vN, P, xca);
  k_gemm2<<<dim3(6, 128), dim3(256), 0, stream>>>(xca, wpb, yp);
  k_final<<<dim3(4096), dim3(256), 0, stream>>>(yp, x, cw, gamma, beta, out);
}

// Round 4
// 256.896 us; speedup vs baseline: 1.2730x; 1.0216x over previous
//
#include <hip/hip_runtime.h>

#define DEVI __device__ __forceinline__

typedef __bf16 bf16x8 __attribute__((ext_vector_type(8)));
typedef float f32x4 __attribute__((ext_vector_type(4)));

// ---------- small helpers ----------
DEVI unsigned short f2bf(float f) {
  unsigned u = __builtin_bit_cast(unsigned, f);
  u += 0x7FFFu + ((u >> 16) & 1u);   // RNE
  return (unsigned short)(u >> 16);
}
DEVI float bf2f(unsigned short s) {
  return __builtin_bit_cast(float, ((unsigned)s) << 16);
}
DEVI f32x4 mfma16(bf16x8 a, bf16x8 b, f32x4 c) {
  return __builtin_amdgcn_mfma_f32_16x16x32_bf16(a, b, c, 0, 0, 0);
}
DEVI void gload16(const void* g, void* l) {
  __builtin_amdgcn_global_load_lds(
      (const __attribute__((address_space(1))) void*)g,
      (__attribute__((address_space(3))) void*)l, 16, 0, 0);
}
// LDS fragment read, rows ROWB bytes, XOR-swizzle byte ^= (row&7)<<4
template <int ROWB>
DEVI bf16x8 frag_ld(const char* lds, int row, int kb) {
  int off = row * ROWB + (kb ^ ((row & 7) << 4));
  return __builtin_bit_cast(bf16x8, *(const uint4*)(lds + off));
}

// ---------- fp32 -> bf16 convert ----------
__global__ __launch_bounds__(256) void k_cvt(const float* __restrict__ in,
                                             unsigned short* __restrict__ out, int n4) {
  int i = blockIdx.x * 256 + threadIdx.x;
  int st = gridDim.x * 256;
  for (; i < n4; i += st) {
    float4 f = ((const float4*)in)[i];
    ushort4 o;
    o.x = f2bf(f.x); o.y = f2bf(f.y); o.z = f2bf(f.z); o.w = f2bf(f.w);
    ((ushort4*)out)[i] = o;
  }
}

// ---------- GEMM1: qkv = x * w_qkv^T ; scatter q^T, k^T, v ----------
// 256x256 tile, BK=64, 8 waves (2M x 4N), pipelined schedule with counted vmcnt
// (never 0 in main loop), raw s_barrier, setprio around MFMA.
// Half-tiles (interleaved so consumption order is wave-uniform):
//   Ah0 = A rows {0-63, 128-191}   (each wr's m-frags 0-3)
//   Ah1 = A rows {64-127, 192-255} (m-frags 4-7)
//   Bh0 = B rows {wc*64+[0,32) for all wc}  (n-frags 0-1)
//   Bh1 = B rows {wc*64+[32,64)}            (n-frags 2-3)
// Issue order per K-tile: Ah0,Bh0,Bh1,Ah1 (2 gload16/thread each).
// Swizzle: LDS[row][cb ^ ((row&7)<<4)] = global[row][cb]  (cb = byte 0..127).
__global__ __launch_bounds__(512, 2) void k_gemm1(const unsigned short* __restrict__ xb,
                                                  const unsigned short* __restrict__ wb,
                                                  unsigned short* __restrict__ qT,
                                                  unsigned short* __restrict__ kT,
                                                  unsigned short* __restrict__ vN) {
  __shared__ alignas(16) char lds[131072];  // 2 bufs x (A 32KB + B 32KB)
  const int tid = threadIdx.x, l = tid & 63, wid = tid >> 6;
  const int wr = wid >> 2, wc = wid & 3;
  const int xg = blockIdx.x;
  const int li = (xg & 7) * 72 + (xg >> 3);   // bijective XCD swizzle (576 = 8*72)
  const int jt = li % 9, mt = li / 9;
  const int m0 = mt * 256, j0 = jt * 256;

  // staging sources: per wave, chunks {2*wid, 2*wid+1} of each half-tile
  const unsigned short* srcg[4][2];
  int ldso[4][2];
#pragma unroll
  for (int ht = 0; ht < 4; ++ht) {
    const bool isA = (ht == 0) || (ht == 3);
    const int h = (ht >= 2) ? 1 : 0;
#pragma unroll
    for (int i = 0; i < 2; ++i) {
      const int c = 2 * wid + i;
      const int r0 = isA ? (h * 64 + 8 * c + ((c & 8) << 3))
                         : ((c >> 2) * 64 + h * 32 + (c & 3) * 8);
      const int r = r0 + (l >> 3);
      const int scol = ((l & 7) ^ (l >> 3)) << 3;  // pre-swizzled source col (elems)
      srcg[ht][i] = (isA ? xb + (size_t)(m0 + r) * 768 : wb + (size_t)(j0 + r) * 768) + scol;
      ldso[ht][i] = (isA ? 0 : 32768) + r0 * 128;
    }
  }
  // fragment read columns: full XOR incl. bit 6 (k-slice bit)
  const int swz = (l & 7) << 4;            // row-stripe swizzle mask (row&7 == l&7)
  const int uu = (l >> 4) << 4;            // k-group byte offset within 64B slice
  const int c0 = uu ^ swz;                 // k-slice 0 column byte
  const int c1 = (64 | uu) ^ swz;          // k-slice 1 column byte
  const int arow = (wr * 128 + (l & 15)) * 128;
  const int brow = 32768 + (wc * 64 + (l & 15)) * 128;

  f32x4 acc[8][4];
#pragma unroll
  for (int i = 0; i < 8; ++i)
#pragma unroll
    for (int j = 0; j < 4; ++j)
#pragma unroll
      for (int e = 0; e < 4; ++e) acc[i][j][e] = 0.f;
  bf16x8 a[4][2], b[4][2];

#define STAGE(ht, nxt, ko)                                        \
  do {                                                            \
    gload16(srcg[ht][0] + (ko), lds + (nxt)*65536 + ldso[ht][0]); \
    gload16(srcg[ht][1] + (ko), lds + (nxt)*65536 + ldso[ht][1]); \
  } while (0)
#define LD128(off) __builtin_bit_cast(bf16x8, *(const uint4*)(cb_ + (off)))

  // prologue: stage K-tile 0, land Ah0+Bh0, keep Bh1+Ah1 in flight
  STAGE(0, 0, 0); STAGE(1, 0, 0); STAGE(2, 0, 0); STAGE(3, 0, 0);
  asm volatile("s_waitcnt vmcnt(4)" ::: "memory");
  __builtin_amdgcn_s_barrier();

#define KBODY(KT, LASTF)                                                              \
  {                                                                                   \
    const char* cb_ = lds + ((KT) & 1) * 65536;                                       \
    const int nxt = (((KT) & 1) ^ 1);                                                 \
    const int ko = ((KT) + 1) * 64;                                                   \
    /* ph0: read Ah0+Bh0 frags, stage Ah0(next) */                                    \
    _Pragma("unroll") for (int mf = 0; mf < 4; ++mf) {                                \
      a[mf][0] = LD128(arow + mf * 2048 + c0);                                        \
      a[mf][1] = LD128(arow + mf * 2048 + c1);                                        \
    }                                                                                 \
    _Pragma("unroll") for (int nf = 0; nf < 2; ++nf) {                                \
      b[nf][0] = LD128(brow + nf * 2048 + c0);                                        \
      b[nf][1] = LD128(brow + nf * 2048 + c1);                                        \
    }                                                                                 \
    if (!(LASTF)) { STAGE(0, nxt, ko); asm volatile("s_waitcnt vmcnt(4)" ::: "memory"); } \
    else          { asm volatile("s_waitcnt vmcnt(2)" ::: "memory"); }                \
    __builtin_amdgcn_s_barrier();                                                     \
    __builtin_amdgcn_s_setprio(1);                                                    \
    _Pragma("unroll") for (int mf = 0; mf < 4; ++mf)                                  \
      _Pragma("unroll") for (int nf = 0; nf < 2; ++nf) {                              \
        acc[mf][nf] = mfma16(a[mf][0], b[nf][0], acc[mf][nf]);                        \
        acc[mf][nf] = mfma16(a[mf][1], b[nf][1], acc[mf][nf]);                        \
      }                                                                               \
    __builtin_amdgcn_s_setprio(0);                                                    \
    /* ph1: read Bh1 frags, stage Bh0(next) */                                        \
    _Pragma("unroll") for (int nf = 2; nf < 4; ++nf) {                                \
      b[nf][0] = LD128(brow + nf * 2048 + c0);                                        \
      b[nf][1] = LD128(brow + nf * 2048 + c1);                                        \
    }                                                                                 \
    if (!(LASTF)) { STAGE(1, nxt, ko); asm volatile("s_waitcnt vmcnt(4)" ::: "memory"); } \
    else          { asm volatile("s_waitcnt vmcnt(0)" ::: "memory"); }                \
    __builtin_amdgcn_s_barrier();                                                     \
    __builtin_amdgcn_s_setprio(1);                                                    \
    _Pragma("unroll") for (int mf = 0; mf < 4; ++mf)                                  \
      _Pragma("unroll") for (int nf = 2; nf < 4; ++nf) {                              \
        acc[mf][nf] = mfma16(a[mf][0], b[nf][0], acc[mf][nf]);                        \
        acc[mf][nf] = mfma16(a[mf][1], b[nf][1], acc[mf][nf]);                        \
      }                                                                               \
    __builtin_amdgcn_s_setprio(0);                                                    \
    /* ph2: read Ah1 frags, stage Bh1(next), no vmcnt */                              \
    _Pragma("unroll") for (int mf = 0; mf < 4; ++mf) {                                \
      a[mf][0] = LD128(arow + (mf + 4) * 2048 + c0);                                  \
      a[mf][1] = LD128(arow + (mf + 4) * 2048 + c1);                                  \
    }                                                                                 \
    if (!(LASTF)) STAGE(2, nxt, ko);                                                  \
    asm volatile("" ::: "memory");                                                    \
    __builtin_amdgcn_s_barrier();                                                     \
    __builtin_amdgcn_s_setprio(1);                                                    \
    _Pragma("unroll") for (int mf = 0; mf < 4; ++mf)                                  \
      _Pragma("unroll") for (int nf = 0; nf < 2; ++nf) {                              \
        acc[mf + 4][nf] = mfma16(a[mf][0], b[nf][0], acc[mf + 4][nf]);                \
        acc[mf + 4][nf] = mfma16(a[mf][1], b[nf][1], acc[mf + 4][nf]);                \
      }                                                                               \
    __builtin_amdgcn_s_setprio(0);                                                    \
    /* ph3: stage Ah1(next), vmcnt(4) lands Ah0+Bh0(next) */                          \
    if (!(LASTF)) { STAGE(3, nxt, ko); asm volatile("s_waitcnt vmcnt(4)" ::: "memory"); } \
    else          { asm volatile("" ::: "memory"); }                                  \
    __builtin_amdgcn_s_barrier();                                                     \
    __builtin_amdgcn_s_setprio(1);                                                    \
    _Pragma("unroll") for (int mf = 0; mf < 4; ++mf)                                  \
      _Pragma("unroll") for (int nf = 2; nf < 4; ++nf) {                              \
        acc[mf + 4][nf] = mfma16(a[mf][0], b[nf][0], acc[mf + 4][nf]);                \
        acc[mf + 4][nf] = mfma16(a[mf][1], b[nf][1], acc[mf + 4][nf]);                \
      }                                                                               \
    __builtin_amdgcn_s_setprio(0);                                                    \
  }

#pragma unroll 1
  for (int kt = 0; kt < 11; ++kt) KBODY(kt, false);
  KBODY(11, true);
#undef KBODY
#undef STAGE
#undef LD128

  // epilogue: scatter to qT/kT (ushort4 along n) or vN (scalar)
  const int s = j0 / 768;  // tile-aligned: 256 | 768
  const int bb = m0 >> 10;
  const int ntok0 = (m0 & 1023) + wr * 128 + ((l >> 4) << 2);
  const int jin0 = (j0 % 768) + wc * 64 + (l & 15);
#pragma unroll
  for (int mf = 0; mf < 8; ++mf) {
    const int n = ntok0 + mf * 16;
#pragma unroll
    for (int nf = 0; nf < 4; ++nf) {
      const int jj = jin0 + nf * 16;
      const int hh = jj / 96, dd = jj % 96;
      if (s == 2) {
        unsigned short* vp = vN + ((size_t)((bb * 8 + hh) * 1024 + n)) * 96 + dd;
#pragma unroll
        for (int rr = 0; rr < 4; ++rr) vp[rr * 96] = f2bf(acc[mf][nf][rr]);
      } else {
        unsigned short* base = (s == 0) ? qT : kT;
        ushort4 pk;
        pk.x = f2bf(acc[mf][nf][0]); pk.y = f2bf(acc[mf][nf][1]);
        pk.z = f2bf(acc[mf][nf][2]); pk.w = f2bf(acc[mf][nf][3]);
        *(ushort4*)(base + ((size_t)((bb * 8 + hh) * 96 + dd)) * 1024 + n) = pk;
      }
    }
  }
}

// ---------- token-dim L2 norms of q,k columns ----------
DEVI float ssq8(uint4 u) {
  unsigned a[4] = {u.x, u.y, u.z, u.w};
  float s = 0.f;
#pragma unroll
  for (int i = 0; i < 4; ++i) {
    float lo = __builtin_bit_cast(float, a[i] << 16);
    float hi = __builtin_bit_cast(float, a[i] & 0xFFFF0000u);
    s += lo * lo + hi * hi;
  }
  return s;
}

__global__ __launch_bounds__(256) void k_norms(const unsigned short* __restrict__ qT,
                                               const unsigned short* __restrict__ kT,
                                               float* __restrict__ nq, float* __restrict__ nk) {
  const int bh = blockIdx.x, tid = threadIdx.x, lane = tid & 63, wid = tid >> 6;
  for (int row = wid; row < 192; row += 4) {
    const unsigned short* src = (row < 96) ? qT + ((size_t)bh * 96 + row) * 1024
                                           : kT + ((size_t)bh * 96 + row - 96) * 1024;
    const uint4* p = (const uint4*)src + lane * 2;
    float s = ssq8(p[0]) + ssq8(p[1]);
#pragma unroll
    for (int off = 32; off; off >>= 1) s += __shfl_xor(s, off, 64);
    if (lane == 0) {
      if (row < 96) nq[bh * 96 + row] = sqrtf(s);
      else          nk[bh * 96 + row - 96] = sqrtf(s);
    }
  }
}

// ---------- A' = q^T k (over N), scale by 1/(|q||k|temp), softmax -> P ----------
__global__ __launch_bounds__(256) void k_attn(const unsigned short* __restrict__ qT,
                                              const unsigned short* __restrict__ kT,
                                              const float* __restrict__ nq,
                                              const float* __restrict__ nk,
                                              const float* __restrict__ temp,
                                              unsigned short* __restrict__ P) {
  __shared__ alignas(16) char lQ[12288];   // [96][64] bf16 swizzled
  __shared__ alignas(16) char lK[12288];
  __shared__ float lA[96 * 96];
  __shared__ float lrq[96], lrk[96];
  const int bh = blockIdx.x, tid = threadIdx.x, lane = tid & 63, wid = tid >> 6;
  if (tid < 96) lrq[tid] = 1.f / fmaxf(nq[bh * 96 + tid], 1e-12f);
  if (tid >= 96 && tid < 192) lrk[tid - 96] = 1.f / fmaxf(nk[bh * 96 + tid - 96], 1e-12f);
  const float invt = 1.f / temp[bh & 7];
  const int wr = wid >> 1, wc = wid & 1;
  const unsigned short* qb = qT + (size_t)bh * 96 * 1024;
  const unsigned short* kb = kT + (size_t)bh * 96 * 1024;

  const unsigned short* srcp[6];
  char* dstp[6];
#pragma unroll
  for (int i = 0; i < 6; ++i) {
    int cid = wid * 6 + i;          // 24 chunks: 12 q + 12 k
    bool isK = cid >= 12;
    int c = isK ? cid - 12 : cid;
    int p = c * 1024 + lane * 16;
    int r = p >> 7, cb = p & 127;
    int cbs = cb ^ ((r & 7) << 4);
    srcp[i] = (isK ? kb : qb) + (size_t)r * 1024 + (cbs >> 1);
    dstp[i] = (isK ? lK : lQ) + c * 1024;
  }

  f32x4 acc[3][3];
#pragma unroll
  for (int i = 0; i < 3; ++i)
#pragma unroll
    for (int j = 0; j < 3; ++j)
#pragma unroll
      for (int e = 0; e < 4; ++e) acc[i][j][e] = 0.f;

  for (int k0 = 0; k0 < 1024; k0 += 64) {
    __syncthreads();
#pragma unroll
    for (int i = 0; i < 6; ++i) gload16(srcp[i] + k0, dstp[i]);
    __syncthreads();
#pragma unroll
    for (int ks = 0; ks < 2; ++ks) {
      const int kb2 = ks * 64 + ((lane >> 4) << 4);
      bf16x8 af[3], bfv[3];
#pragma unroll
      for (int mb = 0; mb < 3; ++mb) af[mb] = frag_ld<128>(lQ, wr * 48 + mb * 16 + (lane & 15), kb2);
#pragma unroll
      for (int nb = 0; nb < 3; ++nb) bfv[nb] = frag_ld<128>(lK, wc * 48 + nb * 16 + (lane & 15), kb2);
#pragma unroll
      for (int mb = 0; mb < 3; ++mb)
#pragma unroll
        for (int nb = 0; nb < 3; ++nb) acc[mb][nb] = mfma16(af[mb], bfv[nb], acc[mb][nb]);
    }
  }

  const int rb = wr * 48 + ((lane >> 4) << 2);
  const int eb = wc * 48 + (lane & 15);
#pragma unroll
  for (int mb = 0; mb < 3; ++mb)
#pragma unroll
    for (int nb = 0; nb < 3; ++nb) {
      int e = eb + nb * 16;
#pragma unroll
      for (int rr = 0; rr < 4; ++rr) {
        int d = rb + mb * 16 + rr;
        lA[d * 96 + e] = acc[mb][nb][rr] * lrq[d] * lrk[e] * invt;
      }
    }
  __syncthreads();
  for (int d = wid; d < 96; d += 4) {
    float v0 = lA[d * 96 + lane];
    float v1 = (lane < 32) ? lA[d * 96 + 64 + lane] : -3.0e38f;
    float mx = fmaxf(v0, v1);
#pragma unroll
    for (int off = 32; off; off >>= 1) mx = fmaxf(mx, __shfl_xor(mx, off, 64));
    float p0 = __expf(v0 - mx);
    float p1 = (lane < 32) ? __expf(v1 - mx) : 0.f;
    float ssum = p0 + p1;
#pragma unroll
    for (int off = 32; off; off >>= 1) ssum += __shfl_xor(ssum, off, 64);
    float rs = 1.f / ssum;
    unsigned short* prow = P + ((size_t)bh * 96 + d) * 96;
    prow[lane] = f2bf(p0 * rs);
    if (lane < 32) prow[64 + lane] = f2bf(p1 * rs);
  }
}

// ---------- x_xca = v @ P^T  -> xca [16384][768] bf16 ----------
__global__ __launch_bounds__(256) void k_pv(const unsigned short* __restrict__ vN,
                                            const unsigned short* __restrict__ P,
                                            unsigned short* __restrict__ xca) {
  __shared__ alignas(16) char lV[128 * 256];  // rows padded to 128 bf16, swizzled
  __shared__ alignas(16) char lP[96 * 256];
  const int bh = blockIdx.x, mt = blockIdx.y;
  const int n0 = mt * 128;
  const int bb = bh >> 3, hh = bh & 7;
  const int tid = threadIdx.x, lane = tid & 63, wid = tid >> 6;
  const int wr = wid >> 1, wc = wid & 1;

  const unsigned short* vb = vN + ((size_t)bh * 1024 + n0) * 96;
  for (int idx = tid; idx < 1536; idx += 256) {  // 128 rows * 12 chunks
    int r = idx / 12, ch = idx % 12;
    uint4 u = *(const uint4*)(vb + (size_t)r * 96 + ch * 8);
    *(uint4*)(lV + r * 256 + ((ch * 16) ^ ((r & 7) << 4))) = u;
  }
  const unsigned short* pb = P + (size_t)bh * 96 * 96;
  for (int idx = tid; idx < 1152; idx += 256) {  // 96 rows * 12 chunks
    int r = idx / 12, ch = idx % 12;
    uint4 u = *(const uint4*)(pb + r * 96 + ch * 8);
    *(uint4*)(lP + r * 256 + ((ch * 16) ^ ((r & 7) << 4))) = u;
  }
  __syncthreads();

  f32x4 acc[4][3];
#pragma unroll
  for (int i = 0; i < 4; ++i)
#pragma unroll
    for (int j = 0; j < 3; ++j)
#pragma unroll
      for (int e = 0; e < 4; ++e) acc[i][j][e] = 0.f;

#pragma unroll
  for (int ks = 0; ks < 3; ++ks) {
    const int kb = ks * 64 + ((lane >> 4) << 4);
    bf16x8 af[4], bfv[3];
#pragma unroll
    for (int mb = 0; mb < 4; ++mb) af[mb] = frag_ld<256>(lV, wr * 64 + mb * 16 + (lane & 15), kb);
#pragma unroll
    for (int nb = 0; nb < 3; ++nb) bfv[nb] = frag_ld<256>(lP, wc * 48 + nb * 16 + (lane & 15), kb);
#pragma unroll
    for (int mb = 0; mb < 4; ++mb)
#pragma unroll
      for (int nb = 0; nb < 3; ++nb) acc[mb][nb] = mfma16(af[mb], bfv[nb], acc[mb][nb]);
  }

  const int nb0 = n0 + wr * 64 + ((lane >> 4) << 2);
  const int db0 = wc * 48 + (lane & 15);
#pragma unroll
  for (int mb = 0; mb < 4; ++mb)
#pragma unroll
    for (int nb = 0; nb < 3; ++nb) {
      int dd = db0 + nb * 16;
#pragma unroll
      for (int rr = 0; rr < 4; ++rr) {
        int n = nb0 + mb * 16 + rr;
        xca[((size_t)(bb * 1024 + n)) * 768 + hh * 96 + dd] = f2bf(acc[mb][nb][rr]);
      }
    }
}

// ---------- GEMM2: yp = xca * w_proj^T (fp32 out) ----------
__global__ __launch_bounds__(256) void k_gemm2(const unsigned short* __restrict__ xca,
                                               const unsigned short* __restrict__ wb,
                                               float* __restrict__ yp) {
  __shared__ alignas(16) char lA[16384];
  __shared__ alignas(16) char lB[16384];
  const int tid = threadIdx.x, lane = tid & 63, wid = tid >> 6;
  const int wr = wid >> 1, wc = wid & 1;
  const int m0 = blockIdx.y * 128, j0 = blockIdx.x * 128;

  const unsigned short* srcp[8];
  char* dstp[8];
#pragma unroll
  for (int i = 0; i < 8; ++i) {
    int cid = wid * 8 + i;
    bool isB = cid >= 16;
    int c = cid & 15;
    int p = c * 1024 + lane * 16;
    int r = p >> 7, cb = p & 127;
    int cbs = cb ^ ((r & 7) << 4);
    srcp[i] = (isB ? wb + (size_t)(j0 + r) * 768 : xca + (size_t)(m0 + r) * 768) + (cbs >> 1);
    dstp[i] = (isB ? lB : lA) + c * 1024;
  }

  f32x4 acc[4][4];
#pragma unroll
  for (int i = 0; i < 4; ++i)
#pragma unroll
    for (int j = 0; j < 4; ++j)
#pragma unroll
      for (int e = 0; e < 4; ++e) acc[i][j][e] = 0.f;

  for (int k0 = 0; k0 < 768; k0 += 64) {
    __syncthreads();
#pragma unroll
    for (int i = 0; i < 8; ++i) gload16(srcp[i] + k0, dstp[i]);
    __syncthreads();
#pragma unroll
    for (int ks = 0; ks < 2; ++ks) {
      const int kb = ks * 64 + ((lane >> 4) << 4);
      bf16x8 af[4], bfv[4];
#pragma unroll
      for (int mb = 0; mb < 4; ++mb) af[mb] = frag_ld<128>(lA, wr * 64 + mb * 16 + (lane & 15), kb);
#pragma unroll
      for (int nb = 0; nb < 4; ++nb) bfv[nb] = frag_ld<128>(lB, wc * 64 + nb * 16 + (lane & 15), kb);
#pragma unroll
      for (int mb = 0; mb < 4; ++mb)
#pragma unroll
        for (int nb = 0; nb < 4; ++nb) acc[mb][nb] = mfma16(af[mb], bfv[nb], acc[mb][nb]);
    }
  }

  const int row0 = m0 + wr * 64 + ((lane >> 4) << 2);
  const int col0 = j0 + wc * 64 + (lane & 15);
#pragma unroll
  for (int mb = 0; mb < 4; ++mb)
#pragma unroll
    for (int nb = 0; nb < 4; ++nb)
#pragma unroll
      for (int rr = 0; rr < 4; ++rr)
        yp[(size_t)(row0 + mb * 16 + rr) * 768 + col0 + nb * 16] = acc[mb][nb][rr];
}

// ---------- final: y = yp + 0.1*dwconv3x3(x); LayerNorm(y)*gamma+beta ----------
// wave-per-token, float4-vectorized: each lane owns 12 channels (3 groups x 4).
__global__ __launch_bounds__(256) void k_final(const float* __restrict__ yp,
                                               const float* __restrict__ x,
                                               const float* __restrict__ cw,
                                               const float* __restrict__ gamma,
                                               const float* __restrict__ beta,
                                               float* __restrict__ out) {
  const int wid = threadIdx.x >> 6, lane = threadIdx.x & 63;
  const int m = blockIdx.x * 4 + wid;           // token id
  const int bb = m >> 10, n = m & 1023, yy = n >> 5, xx = n & 31;
  const float* xb = x + (size_t)bb * 1024 * 768;

  float yv[3][4];
#pragma unroll
  for (int g = 0; g < 3; ++g) {
    const int c = g * 256 + lane * 4;
    // conv weights for channels c..c+3: 36 consecutive floats, 16B-aligned
    float w36[36];
    const float4* wp = (const float4*)(cw + (size_t)c * 9);
#pragma unroll
    for (int i = 0; i < 9; ++i) *(float4*)(w36 + i * 4) = wp[i];

    float a0 = 0.f, a1 = 0.f, a2 = 0.f, a3 = 0.f;
#pragma unroll
    for (int dy = -1; dy <= 1; ++dy) {
      int ny = yy + dy;
      if ((unsigned)ny < 32u) {
#pragma unroll
        for (int dx = -1; dx <= 1; ++dx) {
          int nx = xx + dx;
          if ((unsigned)nx < 32u) {
            float4 v = *(const float4*)(xb + (size_t)(ny * 32 + nx) * 768 + c);
            const int j = (dy + 1) * 3 + (dx + 1);
            a0 += w36[0 * 9 + j] * v.x;
            a1 += w36[1 * 9 + j] * v.y;
            a2 += w36[2 * 9 + j] * v.z;
            a3 += w36[3 * 9 + j] * v.w;
          }
        }
      }
    }
    float4 f = *(const float4*)(yp + (size_t)m * 768 + c);
    yv[g][0] = f.x + 0.1f * a0;
    yv[g][1] = f.y + 0.1f * a1;
    yv[g][2] = f.z + 0.1f * a2;
    yv[g][3] = f.w + 0.1f * a3;
  }

  float s1 = 0.f, s2 = 0.f;
#pragma unroll
  for (int g = 0; g < 3; ++g)
#pragma unroll
    for (int e = 0; e < 4; ++e) { s1 += yv[g][e]; s2 += yv[g][e] * yv[g][e]; }
#pragma unroll
  for (int off = 32; off; off >>= 1) {
    s1 += __shfl_xor(s1, off, 64);
    s2 += __shfl_xor(s2, off, 64);
  }
  const float mu = s1 * (1.f / 768.f);
  const float var = s2 * (1.f / 768.f) - mu * mu;
  const float rs = rsqrtf(var + 1e-5f);

#pragma unroll
  for (int g = 0; g < 3; ++g) {
    const int c = g * 256 + lane * 4;
    float4 gm = *(const float4*)(gamma + c);
    float4 bt = *(const float4*)(beta + c);
    float4 o;
    o.x = (yv[g][0] - mu) * rs * gm.x + bt.x;
    o.y = (yv[g][1] - mu) * rs * gm.y + bt.y;
    o.z = (yv[g][2] - mu) * rs * gm.z + bt.z;
    o.w = (yv[g][3] - mu) * rs * gm.w + bt.w;
    *(float4*)(out + (size_t)m * 768 + c) = o;
  }
}

// ---------- host ----------
extern "C" void kernel_launch(void* const* d_in, const int* in_sizes, int n_in,
                              void* d_out, int out_size, void* d_ws, size_t ws_size,
                              hipStream_t stream) {
  const float* x     = (const float*)d_in[0];
  const float* wqkv  = (const float*)d_in[1];
  const float* wproj = (const float*)d_in[2];
  const float* temp  = (const float*)d_in[3];
  const float* cw    = (const float*)d_in[4];
  const float* gamma = (const float*)d_in[5];
  const float* beta  = (const float*)d_in[6];
  float* out = (float*)d_out;
  char* ws = (char*)d_ws;

  // workspace layout (all offsets 256B-aligned); total ~103 MiB
  unsigned short* xb  = (unsigned short*)(ws);               // 25165824 B (reused as xca)
  unsigned short* wqb = (unsigned short*)(ws + 25165824);    // 3538944
  unsigned short* wpb = (unsigned short*)(ws + 28704768);    // 1179648
  unsigned short* qT  = (unsigned short*)(ws + 29884416);    // 25165824
  unsigned short* kT  = (unsigned short*)(ws + 55050240);    // 25165824
  unsigned short* vN  = (unsigned short*)(ws + 80216064);    // 25165824
  float* nq           = (float*)(ws + 105381888);            // 49152
  float* nk           = (float*)(ws + 105431040);            // 49152
  unsigned short* P   = (unsigned short*)(ws + 105480192);   // 2359296
  float* yp           = (float*)(ws + 29884416);             // aliases qT+kT (dead by then)
  unsigned short* xca = xb;                                  // aliases xb (dead by then)

  k_cvt<<<dim3(2048), dim3(256), 0, stream>>>(x, xb, 16384 * 768 / 4);
  k_cvt<<<dim3(1728), dim3(256), 0, stream>>>(wqkv, wqb, 2304 * 768 / 4);
  k_cvt<<<dim3(576), dim3(256), 0, stream>>>(wproj, wpb, 768 * 768 / 4);
  k_gemm1<<<dim3(576), dim3(512), 0, stream>>>(xb, wqb, qT, kT, vN);
  k_norms<<<dim3(128), dim3(256), 0, stream>>>(qT, kT, nq, nk);
  k_attn<<<dim3(128), dim3(256), 0, stream>>>(qT, kT, nq, nk, temp, P);
  k_pv<<<dim3(128, 8), dim3(256), 0, stream>>>(vN, P, xca);
  k_gemm2<<<dim3(6, 128), dim3(256), 0, stream>>>(xca, wpb, yp);
  k_final<<<dim3(4096), dim3(256), 0, stream>>>(yp, x, cw, gamma, beta, out);
}

// Round 5
// 252.808 us; speedup vs baseline: 1.2935x; 1.0162x over previous
//
#include <hip/hip_runtime.h>

#define DEVI __device__ __forceinline__

typedef __bf16 bf16x8 __attribute__((ext_vector_type(8)));
typedef float f32x4 __attribute__((ext_vector_type(4)));

// ---------- small helpers ----------
DEVI unsigned short f2bf(float f) {
  unsigned u = __builtin_bit_cast(unsigned, f);
  u += 0x7FFFu + ((u >> 16) & 1u);   // RNE
  return (unsigned short)(u >> 16);
}
DEVI float bf2f(unsigned short s) {
  return __builtin_bit_cast(float, ((unsigned)s) << 16);
}
DEVI f32x4 mfma16(bf16x8 a, bf16x8 b, f32x4 c) {
  return __builtin_amdgcn_mfma_f32_16x16x32_bf16(a, b, c, 0, 0, 0);
}
DEVI void gload16(const void* g, void* l) {
  __builtin_amdgcn_global_load_lds(
      (const __attribute__((address_space(1))) void*)g,
      (__attribute__((address_space(3))) void*)l, 16, 0, 0);
}
// LDS fragment read, rows ROWB bytes, XOR-swizzle byte ^= (row&7)<<4
template <int ROWB>
DEVI bf16x8 frag_ld(const char* lds, int row, int kb) {
  int off = row * ROWB + (kb ^ ((row & 7) << 4));
  return __builtin_bit_cast(bf16x8, *(const uint4*)(lds + off));
}

// ---------- fp32 -> bf16 convert ----------
__global__ __launch_bounds__(256) void k_cvt(const float* __restrict__ in,
                                             unsigned short* __restrict__ out, int n4) {
  int i = blockIdx.x * 256 + threadIdx.x;
  int st = gridDim.x * 256;
  for (; i < n4; i += st) {
    float4 f = ((const float4*)in)[i];
    ushort4 o;
    o.x = f2bf(f.x); o.y = f2bf(f.y); o.z = f2bf(f.z); o.w = f2bf(f.w);
    ((ushort4*)out)[i] = o;
  }
}

// ---------- GEMM1: qkv = x * w_qkv^T ; scatter q^T, k^T, v ----------
// 256x192 tile, BK=64, 8 waves (2M x 4N), pipelined schedule with counted vmcnt
// (never 0 in main loop), raw s_barrier, setprio around MFMA.
// Grid = 64 mt x 12 jt = 768 blocks = exactly 3 rounds over 256 CUs (no tail).
// Half-tiles (interleaved so consumption order is wave-uniform):
//   Ah0 = A rows {0-63, 128-191}   (each wr's m-frags 0-3)   16 chunks
//   Ah1 = A rows {64-127, 192-255} (m-frags 4-7)             16 chunks
//   Bh0 = B rows {wc*48+[0,32)}    (n-frags 0-1)             16 chunks
//   Bh1 = B rows {wc*48+[32,48)}   (n-frag 2)                 8 chunks
// Per-thread loads per K-tile: Ah0:2 Bh0:2 Bh1:1 Ah1:2 (7 total).
// Swizzle: LDS[row][cb ^ ((row&7)<<4)] = global[row][cb]  (cb = byte 0..127).
__global__ __launch_bounds__(512, 2) void k_gemm1(const unsigned short* __restrict__ xb,
                                                  const unsigned short* __restrict__ wb,
                                                  unsigned short* __restrict__ qT,
                                                  unsigned short* __restrict__ kT,
                                                  unsigned short* __restrict__ vN) {
  __shared__ alignas(16) char lds[114688];  // 2 bufs x (A 32KB + B 24KB)
  const int tid = threadIdx.x, l = tid & 63, wid = tid >> 6;
  const int wr = wid >> 2, wc = wid & 3;
  const int xg = blockIdx.x;
  const int li = (xg & 7) * 96 + (xg >> 3);   // bijective XCD swizzle (768 = 8*96)
  const int jt = li % 12, mt = li / 12;
  const int m0 = mt * 256, j0 = jt * 192;

  // staging sources (chunks of 1KB = 8 rows x 128B)
  const unsigned short* srcg[4][2];
  int ldso[4][2];
#pragma unroll
  for (int ht = 0; ht < 4; ++ht) {
    const bool isA = (ht == 0) || (ht == 3);
#pragma unroll
    for (int i = 0; i < 2; ++i) {
      const int c = (ht == 2) ? wid : (2 * wid + i);
      int r0;
      if (ht == 0)      r0 = 8 * c + ((c & 8) << 3);
      else if (ht == 3) r0 = 64 + 8 * c + ((c & 8) << 3);
      else if (ht == 1) r0 = (c >> 2) * 48 + (c & 3) * 8;
      else              r0 = (c >> 1) * 48 + 32 + (c & 1) * 8;
      const int r = r0 + (l >> 3);
      const int scol = ((l & 7) ^ (l >> 3)) << 3;  // pre-swizzled source col (elems)
      srcg[ht][i] = (isA ? xb + (size_t)(m0 + r) * 768 : wb + (size_t)(j0 + r) * 768) + scol;
      ldso[ht][i] = (isA ? 0 : 32768) + r0 * 128;
    }
  }
  // fragment read columns: full XOR incl. bit 6 (k-slice bit)
  const int swz = (l & 7) << 4;            // row-stripe swizzle mask (row&7 == l&7)
  const int uu = (l >> 4) << 4;            // k-group byte offset within 64B slice
  const int c0 = uu ^ swz;                 // k-slice 0 column byte
  const int c1 = (64 | uu) ^ swz;          // k-slice 1 column byte
  const int arow = (wr * 128 + (l & 15)) * 128;
  const int brow = 32768 + (wc * 48 + (l & 15)) * 128;

  f32x4 acc[8][3];
#pragma unroll
  for (int i = 0; i < 8; ++i)
#pragma unroll
    for (int j = 0; j < 3; ++j)
#pragma unroll
      for (int e = 0; e < 4; ++e) acc[i][j][e] = 0.f;
  bf16x8 a[4][2], b[3][2];

#define STAGE2(ht, nxt, ko)                                         \
  do {                                                              \
    gload16(srcg[ht][0] + (ko), lds + (nxt)*57344 + ldso[ht][0]);   \
    gload16(srcg[ht][1] + (ko), lds + (nxt)*57344 + ldso[ht][1]);   \
  } while (0)
#define STAGE1(ht, nxt, ko)                                         \
  gload16(srcg[ht][0] + (ko), lds + (nxt)*57344 + ldso[ht][0])
#define LD128(off) __builtin_bit_cast(bf16x8, *(const uint4*)(cb_ + (off)))

  // prologue: stage K-tile 0 (7 loads), land Ah0+Bh0, keep Bh1+Ah1 (3) in flight
  STAGE2(0, 0, 0); STAGE2(1, 0, 0); STAGE1(2, 0, 0); STAGE2(3, 0, 0);
  asm volatile("s_waitcnt vmcnt(3)" ::: "memory");
  __builtin_amdgcn_s_barrier();

#define KBODY(KT, LASTF)                                                              \
  {                                                                                   \
    const char* cb_ = lds + ((KT) & 1) * 57344;                                       \
    const int nxt = (((KT) & 1) ^ 1);                                                 \
    const int ko = ((KT) + 1) * 64;                                                   \
    /* ph0: read Ah0 + Bh0 frags, stage Ah0(next) */                                  \
    _Pragma("unroll") for (int mf = 0; mf < 4; ++mf) {                                \
      a[mf][0] = LD128(arow + mf * 2048 + c0);                                        \
      a[mf][1] = LD128(arow + mf * 2048 + c1);                                        \
    }                                                                                 \
    _Pragma("unroll") for (int nf = 0; nf < 2; ++nf) {                                \
      b[nf][0] = LD128(brow + nf * 2048 + c0);                                        \
      b[nf][1] = LD128(brow + nf * 2048 + c1);                                        \
    }                                                                                 \
    if (!(LASTF)) { STAGE2(0, nxt, ko); asm volatile("s_waitcnt vmcnt(4)" ::: "memory"); } \
    else          { asm volatile("s_waitcnt vmcnt(2)" ::: "memory"); }                \
    __builtin_amdgcn_s_barrier();                                                     \
    __builtin_amdgcn_s_setprio(1);                                                    \
    _Pragma("unroll") for (int mf = 0; mf < 4; ++mf)                                  \
      _Pragma("unroll") for (int nf = 0; nf < 2; ++nf) {                              \
        acc[mf][nf] = mfma16(a[mf][0], b[nf][0], acc[mf][nf]);                        \
        acc[mf][nf] = mfma16(a[mf][1], b[nf][1], acc[mf][nf]);                        \
      }                                                                               \
    __builtin_amdgcn_s_setprio(0);                                                    \
    /* ph1: read Bh1 frag, stage Bh0(next) */                                         \
    b[2][0] = LD128(brow + 2 * 2048 + c0);                                            \
    b[2][1] = LD128(brow + 2 * 2048 + c1);                                            \
    if (!(LASTF)) { STAGE2(1, nxt, ko); asm volatile("s_waitcnt vmcnt(4)" ::: "memory"); } \
    else          { asm volatile("s_waitcnt vmcnt(0)" ::: "memory"); }                \
    __builtin_amdgcn_s_barrier();                                                     \
    __builtin_amdgcn_s_setprio(1);                                                    \
    _Pragma("unroll") for (int mf = 0; mf < 4; ++mf) {                                \
      acc[mf][2] = mfma16(a[mf][0], b[2][0], acc[mf][2]);                             \
      acc[mf][2] = mfma16(a[mf][1], b[2][1], acc[mf][2]);                             \
    }                                                                                 \
    __builtin_amdgcn_s_setprio(0);                                                    \
    /* ph2: read Ah1 frags, stage Bh1(next), no vmcnt */                              \
    _Pragma("unroll") for (int mf = 0; mf < 4; ++mf) {                                \
      a[mf][0] = LD128(arow + (mf + 4) * 2048 + c0);                                  \
      a[mf][1] = LD128(arow + (mf + 4) * 2048 + c1);                                  \
    }                                                                                 \
    if (!(LASTF)) STAGE1(2, nxt, ko);                                                 \
    asm volatile("" ::: "memory");                                                    \
    __builtin_amdgcn_s_barrier();                                                     \
    __builtin_amdgcn_s_setprio(1);                                                    \
    _Pragma("unroll") for (int mf = 0; mf < 4; ++mf)                                  \
      _Pragma("unroll") for (int nf = 0; nf < 2; ++nf) {                              \
        acc[mf + 4][nf] = mfma16(a[mf][0], b[nf][0], acc[mf + 4][nf]);                \
        acc[mf + 4][nf] = mfma16(a[mf][1], b[nf][1], acc[mf + 4][nf]);                \
      }                                                                               \
    __builtin_amdgcn_s_setprio(0);                                                    \
    /* ph3: stage Ah1(next), vmcnt(3) lands Ah0+Bh0(next) */                          \
    if (!(LASTF)) { STAGE2(3, nxt, ko); asm volatile("s_waitcnt vmcnt(3)" ::: "memory"); } \
    else          { asm volatile("" ::: "memory"); }                                  \
    __builtin_amdgcn_s_barrier();                                                     \
    __builtin_amdgcn_s_setprio(1);                                                    \
    _Pragma("unroll") for (int mf = 0; mf < 4; ++mf) {                                \
      acc[mf + 4][2] = mfma16(a[mf][0], b[2][0], acc[mf + 4][2]);                     \
      acc[mf + 4][2] = mfma16(a[mf][1], b[2][1], acc[mf + 4][2]);                     \
    }                                                                                 \
    __builtin_amdgcn_s_setprio(0);                                                    \
  }

#pragma unroll 1
  for (int kt = 0; kt < 11; ++kt) KBODY(kt, false);
  KBODY(11, true);
#undef KBODY
#undef STAGE2
#undef STAGE1
#undef LD128

  // epilogue: scatter to qT/kT (ushort4 along n) or vN (scalar)
  const int s = j0 / 768;  // jt 0-3 -> q, 4-7 -> k, 8-11 -> v (4*192 = 768)
  const int bb = m0 >> 10;
  const int ntok0 = (m0 & 1023) + wr * 128 + ((l >> 4) << 2);
  const int jin0 = (j0 % 768) + wc * 48 + (l & 15);
#pragma unroll
  for (int mf = 0; mf < 8; ++mf) {
    const int n = ntok0 + mf * 16;
#pragma unroll
    for (int nf = 0; nf < 3; ++nf) {
      const int jj = jin0 + nf * 16;
      const int hh = jj / 96, dd = jj % 96;
      if (s == 2) {
        unsigned short* vp = vN + ((size_t)((bb * 8 + hh) * 1024 + n)) * 96 + dd;
#pragma unroll
        for (int rr = 0; rr < 4; ++rr) vp[rr * 96] = f2bf(acc[mf][nf][rr]);
      } else {
        unsigned short* base = (s == 0) ? qT : kT;
        ushort4 pk;
        pk.x = f2bf(acc[mf][nf][0]); pk.y = f2bf(acc[mf][nf][1]);
        pk.z = f2bf(acc[mf][nf][2]); pk.w = f2bf(acc[mf][nf][3]);
        *(ushort4*)(base + ((size_t)((bb * 8 + hh) * 96 + dd)) * 1024 + n) = pk;
      }
    }
  }
}

// ---------- token-dim L2 norms of q,k columns ----------
DEVI float ssq8(uint4 u) {
  unsigned a[4] = {u.x, u.y, u.z, u.w};
  float s = 0.f;
#pragma unroll
  for (int i = 0; i < 4; ++i) {
    float lo = __builtin_bit_cast(float, a[i] << 16);
    float hi = __builtin_bit_cast(float, a[i] & 0xFFFF0000u);
    s += lo * lo + hi * hi;
  }
  return s;
}

__global__ __launch_bounds__(256) void k_norms(const unsigned short* __restrict__ qT,
                                               const unsigned short* __restrict__ kT,
                                               float* __restrict__ nq, float* __restrict__ nk) {
  const int bh = blockIdx.x, tid = threadIdx.x, lane = tid & 63, wid = tid >> 6;
  for (int row = wid; row < 192; row += 4) {
    const unsigned short* src = (row < 96) ? qT + ((size_t)bh * 96 + row) * 1024
                                           : kT + ((size_t)bh * 96 + row - 96) * 1024;
    const uint4* p = (const uint4*)src + lane * 2;
    float s = ssq8(p[0]) + ssq8(p[1]);
#pragma unroll
    for (int off = 32; off; off >>= 1) s += __shfl_xor(s, off, 64);
    if (lane == 0) {
      if (row < 96) nq[bh * 96 + row] = sqrtf(s);
      else          nk[bh * 96 + row - 96] = sqrtf(s);
    }
  }
}

// ---------- A' = q^T k (over N), scale by 1/(|q||k|temp), softmax -> P ----------
__global__ __launch_bounds__(256) void k_attn(const unsigned short* __restrict__ qT,
                                              const unsigned short* __restrict__ kT,
                                              const float* __restrict__ nq,
                                              const float* __restrict__ nk,
                                              const float* __restrict__ temp,
                                              unsigned short* __restrict__ P) {
  __shared__ alignas(16) char lQ[12288];   // [96][64] bf16 swizzled
  __shared__ alignas(16) char lK[12288];
  __shared__ float lA[96 * 96];
  __shared__ float lrq[96], lrk[96];
  const int bh = blockIdx.x, tid = threadIdx.x, lane = tid & 63, wid = tid >> 6;
  if (tid < 96) lrq[tid] = 1.f / fmaxf(nq[bh * 96 + tid], 1e-12f);
  if (tid >= 96 && tid < 192) lrk[tid - 96] = 1.f / fmaxf(nk[bh * 96 + tid - 96], 1e-12f);
  const float invt = 1.f / temp[bh & 7];
  const int wr = wid >> 1, wc = wid & 1;
  const unsigned short* qb = qT + (size_t)bh * 96 * 1024;
  const unsigned short* kb = kT + (size_t)bh * 96 * 1024;

  const unsigned short* srcp[6];
  char* dstp[6];
#pragma unroll
  for (int i = 0; i < 6; ++i) {
    int cid = wid * 6 + i;          // 24 chunks: 12 q + 12 k
    bool isK = cid >= 12;
    int c = isK ? cid - 12 : cid;
    int p = c * 1024 + lane * 16;
    int r = p >> 7, cb = p & 127;
    int cbs = cb ^ ((r & 7) << 4);
    srcp[i] = (isK ? kb : qb) + (size_t)r * 1024 + (cbs >> 1);
    dstp[i] = (isK ? lK : lQ) + c * 1024;
  }

  f32x4 acc[3][3];
#pragma unroll
  for (int i = 0; i < 3; ++i)
#pragma unroll
    for (int j = 0; j < 3; ++j)
#pragma unroll
      for (int e = 0; e < 4; ++e) acc[i][j][e] = 0.f;

  for (int k0 = 0; k0 < 1024; k0 += 64) {
    __syncthreads();
#pragma unroll
    for (int i = 0; i < 6; ++i) gload16(srcp[i] + k0, dstp[i]);
    __syncthreads();
#pragma unroll
    for (int ks = 0; ks < 2; ++ks) {
      const int kb2 = ks * 64 + ((lane >> 4) << 4);
      bf16x8 af[3], bfv[3];
#pragma unroll
      for (int mb = 0; mb < 3; ++mb) af[mb] = frag_ld<128>(lQ, wr * 48 + mb * 16 + (lane & 15), kb2);
#pragma unroll
      for (int nb = 0; nb < 3; ++nb) bfv[nb] = frag_ld<128>(lK, wc * 48 + nb * 16 + (lane & 15), kb2);
#pragma unroll
      for (int mb = 0; mb < 3; ++mb)
#pragma unroll
        for (int nb = 0; nb < 3; ++nb) acc[mb][nb] = mfma16(af[mb], bfv[nb], acc[mb][nb]);
    }
  }

  const int rb = wr * 48 + ((lane >> 4) << 2);
  const int eb = wc * 48 + (lane & 15);
#pragma unroll
  for (int mb = 0; mb < 3; ++mb)
#pragma unroll
    for (int nb = 0; nb < 3; ++nb) {
      int e = eb + nb * 16;
#pragma unroll
      for (int rr = 0; rr < 4; ++rr) {
        int d = rb + mb * 16 + rr;
        lA[d * 96 + e] = acc[mb][nb][rr] * lrq[d] * lrk[e] * invt;
      }
    }
  __syncthreads();
  for (int d = wid; d < 96; d += 4) {
    float v0 = lA[d * 96 + lane];
    float v1 = (lane < 32) ? lA[d * 96 + 64 + lane] : -3.0e38f;
    float mx = fmaxf(v0, v1);
#pragma unroll
    for (int off = 32; off; off >>= 1) mx = fmaxf(mx, __shfl_xor(mx, off, 64));
    float p0 = __expf(v0 - mx);
    float p1 = (lane < 32) ? __expf(v1 - mx) : 0.f;
    float ssum = p0 + p1;
#pragma unroll
    for (int off = 32; off; off >>= 1) ssum += __shfl_xor(ssum, off, 64);
    float rs = 1.f / ssum;
    unsigned short* prow = P + ((size_t)bh * 96 + d) * 96;
    prow[lane] = f2bf(p0 * rs);
    if (lane < 32) prow[64 + lane] = f2bf(p1 * rs);
  }
}

// ---------- x_xca = v @ P^T  -> xca [16384][768] bf16 ----------
__global__ __launch_bounds__(256) void k_pv(const unsigned short* __restrict__ vN,
                                            const unsigned short* __restrict__ P,
                                            unsigned short* __restrict__ xca) {
  __shared__ alignas(16) char lV[128 * 256];  // rows padded to 128 bf16, swizzled
  __shared__ alignas(16) char lP[96 * 256];
  const int bh = blockIdx.x, mt = blockIdx.y;
  const int n0 = mt * 128;
  const int bb = bh >> 3, hh = bh & 7;
  const int tid = threadIdx.x, lane = tid & 63, wid = tid >> 6;
  const int wr = wid >> 1, wc = wid & 1;

  const unsigned short* vb = vN + ((size_t)bh * 1024 + n0) * 96;
  for (int idx = tid; idx < 1536; idx += 256) {  // 128 rows * 12 chunks
    int r = idx / 12, ch = idx % 12;
    uint4 u = *(const uint4*)(vb + (size_t)r * 96 + ch * 8);
    *(uint4*)(lV + r * 256 + ((ch * 16) ^ ((r & 7) << 4))) = u;
  }
  const unsigned short* pb = P + (size_t)bh * 96 * 96;
  for (int idx = tid; idx < 1152; idx += 256) {  // 96 rows * 12 chunks
    int r = idx / 12, ch = idx % 12;
    uint4 u = *(const uint4*)(pb + r * 96 + ch * 8);
    *(uint4*)(lP + r * 256 + ((ch * 16) ^ ((r & 7) << 4))) = u;
  }
  __syncthreads();

  f32x4 acc[4][3];
#pragma unroll
  for (int i = 0; i < 4; ++i)
#pragma unroll
    for (int j = 0; j < 3; ++j)
#pragma unroll
      for (int e = 0; e < 4; ++e) acc[i][j][e] = 0.f;

#pragma unroll
  for (int ks = 0; ks < 3; ++ks) {
    const int kb = ks * 64 + ((lane >> 4) << 4);
    bf16x8 af[4], bfv[3];
#pragma unroll
    for (int mb = 0; mb < 4; ++mb) af[mb] = frag_ld<256>(lV, wr * 64 + mb * 16 + (lane & 15), kb);
#pragma unroll
    for (int nb = 0; nb < 3; ++nb) bfv[nb] = frag_ld<256>(lP, wc * 48 + nb * 16 + (lane & 15), kb);
#pragma unroll
    for (int mb = 0; mb < 4; ++mb)
#pragma unroll
      for (int nb = 0; nb < 3; ++nb) acc[mb][nb] = mfma16(af[mb], bfv[nb], acc[mb][nb]);
  }

  const int nb0 = n0 + wr * 64 + ((lane >> 4) << 2);
  const int db0 = wc * 48 + (lane & 15);
#pragma unroll
  for (int mb = 0; mb < 4; ++mb)
#pragma unroll
    for (int nb = 0; nb < 3; ++nb) {
      int dd = db0 + nb * 16;
#pragma unroll
      for (int rr = 0; rr < 4; ++rr) {
        int n = nb0 + mb * 16 + rr;
        xca[((size_t)(bb * 1024 + n)) * 768 + hh * 96 + dd] = f2bf(acc[mb][nb][rr]);
      }
    }
}

// ---------- GEMM2: yp = xca * w_proj^T (fp32 out) ----------
__global__ __launch_bounds__(256) void k_gemm2(const unsigned short* __restrict__ xca,
                                               const unsigned short* __restrict__ wb,
                                               float* __restrict__ yp) {
  __shared__ alignas(16) char lA[16384];
  __shared__ alignas(16) char lB[16384];
  const int tid = threadIdx.x, lane = tid & 63, wid = tid >> 6;
  const int wr = wid >> 1, wc = wid & 1;
  const int m0 = blockIdx.y * 128, j0 = blockIdx.x * 128;

  const unsigned short* srcp[8];
  char* dstp[8];
#pragma unroll
  for (int i = 0; i < 8; ++i) {
    int cid = wid * 8 + i;
    bool isB = cid >= 16;
    int c = cid & 15;
    int p = c * 1024 + lane * 16;
    int r = p >> 7, cb = p & 127;
    int cbs = cb ^ ((r & 7) << 4);
    srcp[i] = (isB ? wb + (size_t)(j0 + r) * 768 : xca + (size_t)(m0 + r) * 768) + (cbs >> 1);
    dstp[i] = (isB ? lB : lA) + c * 1024;
  }

  f32x4 acc[4][4];
#pragma unroll
  for (int i = 0; i < 4; ++i)
#pragma unroll
    for (int j = 0; j < 4; ++j)
#pragma unroll
      for (int e = 0; e < 4; ++e) acc[i][j][e] = 0.f;

  for (int k0 = 0; k0 < 768; k0 += 64) {
    __syncthreads();
#pragma unroll
    for (int i = 0; i < 8; ++i) gload16(srcp[i] + k0, dstp[i]);
    __syncthreads();
#pragma unroll
    for (int ks = 0; ks < 2; ++ks) {
      const int kb = ks * 64 + ((lane >> 4) << 4);
      bf16x8 af[4], bfv[4];
#pragma unroll
      for (int mb = 0; mb < 4; ++mb) af[mb] = frag_ld<128>(lA, wr * 64 + mb * 16 + (lane & 15), kb);
#pragma unroll
      for (int nb = 0; nb < 4; ++nb) bfv[nb] = frag_ld<128>(lB, wc * 64 + nb * 16 + (lane & 15), kb);
#pragma unroll
      for (int mb = 0; mb < 4; ++mb)
#pragma unroll
        for (int nb = 0; nb < 4; ++nb) acc[mb][nb] = mfma16(af[mb], bfv[nb], acc[mb][nb]);
    }
  }

  const int row0 = m0 + wr * 64 + ((lane >> 4) << 2);
  const int col0 = j0 + wc * 64 + (lane & 15);
#pragma unroll
  for (int mb = 0; mb < 4; ++mb)
#pragma unroll
    for (int nb = 0; nb < 4; ++nb)
#pragma unroll
      for (int rr = 0; rr < 4; ++rr)
        yp[(size_t)(row0 + mb * 16 + rr) * 768 + col0 + nb * 16] = acc[mb][nb][rr];
}

// ---------- final: y = yp + 0.1*dwconv3x3(x); LayerNorm(y)*gamma+beta ----------
// wave-per-token, float4-vectorized: each lane owns 12 channels (3 groups x 4).
__global__ __launch_bounds__(256) void k_final(const float* __restrict__ yp,
                                               const float* __restrict__ x,
                                               const float* __restrict__ cw,
                                               const float* __restrict__ gamma,
                                               const float* __restrict__ beta,
                                               float* __restrict__ out) {
  const int wid = threadIdx.x >> 6, lane = threadIdx.x & 63;
  const int m = blockIdx.x * 4 + wid;           // token id
  const int bb = m >> 10, n = m & 1023, yy = n >> 5, xx = n & 31;
  const float* xb = x + (size_t)bb * 1024 * 768;

  float yv[3][4];
#pragma unroll
  for (int g = 0; g < 3; ++g) {
    const int c = g * 256 + lane * 4;
    // conv weights for channels c..c+3: 36 consecutive floats, 16B-aligned
    float w36[36];
    const float4* wp = (const float4*)(cw + (size_t)c * 9);
#pragma unroll
    for (int i = 0; i < 9; ++i) *(float4*)(w36 + i * 4) = wp[i];

    float a0 = 0.f, a1 = 0.f, a2 = 0.f, a3 = 0.f;
#pragma unroll
    for (int dy = -1; dy <= 1; ++dy) {
      int ny = yy + dy;
      if ((unsigned)ny < 32u) {
#pragma unroll
        for (int dx = -1; dx <= 1; ++dx) {
          int nx = xx + dx;
          if ((unsigned)nx < 32u) {
            float4 v = *(const float4*)(xb + (size_t)(ny * 32 + nx) * 768 + c);
            const int j = (dy + 1) * 3 + (dx + 1);
            a0 += w36[0 * 9 + j] * v.x;
            a1 += w36[1 * 9 + j] * v.y;
            a2 += w36[2 * 9 + j] * v.z;
            a3 += w36[3 * 9 + j] * v.w;
          }
        }
      }
    }
    float4 f = *(const float4*)(yp + (size_t)m * 768 + c);
    yv[g][0] = f.x + 0.1f * a0;
    yv[g][1] = f.y + 0.1f * a1;
    yv[g][2] = f.z + 0.1f * a2;
    yv[g][3] = f.w + 0.1f * a3;
  }

  float s1 = 0.f, s2 = 0.f;
#pragma unroll
  for (int g = 0; g < 3; ++g)
#pragma unroll
    for (int e = 0; e < 4; ++e) { s1 += yv[g][e]; s2 += yv[g][e] * yv[g][e]; }
#pragma unroll
  for (int off = 32; off; off >>= 1) {
    s1 += __shfl_xor(s1, off, 64);
    s2 += __shfl_xor(s2, off, 64);
  }
  const float mu = s1 * (1.f / 768.f);
  const float var = s2 * (1.f / 768.f) - mu * mu;
  const float rs = rsqrtf(var + 1e-5f);

#pragma unroll
  for (int g = 0; g < 3; ++g) {
    const int c = g * 256 + lane * 4;
    float4 gm = *(const float4*)(gamma + c);
    float4 bt = *(const float4*)(beta + c);
    float4 o;
    o.x = (yv[g][0] - mu) * rs * gm.x + bt.x;
    o.y = (yv[g][1] - mu) * rs * gm.y + bt.y;
    o.z = (yv[g][2] - mu) * rs * gm.z + bt.z;
    o.w = (yv[g][3] - mu) * rs * gm.w + bt.w;
    *(float4*)(out + (size_t)m * 768 + c) = o;
  }
}

// ---------- host ----------
extern "C" void kernel_launch(void* const* d_in, const int* in_sizes, int n_in,
                              void* d_out, int out_size, void* d_ws, size_t ws_size,
                              hipStream_t stream) {
  const float* x     = (const float*)d_in[0];
  const float* wqkv  = (const float*)d_in[1];
  const float* wproj = (const float*)d_in[2];
  const float* temp  = (const float*)d_in[3];
  const float* cw    = (const float*)d_in[4];
  const float* gamma = (const float*)d_in[5];
  const float* beta  = (const float*)d_in[6];
  float* out = (float*)d_out;
  char* ws = (char*)d_ws;

  // workspace layout (all offsets 256B-aligned); total ~103 MiB
  unsigned short* xb  = (unsigned short*)(ws);               // 25165824 B (reused as xca)
  unsigned short* wqb = (unsigned short*)(ws + 25165824);    // 3538944
  unsigned short* wpb = (unsigned short*)(ws + 28704768);    // 1179648
  unsigned short* qT  = (unsigned short*)(ws + 29884416);    // 25165824
  unsigned short* kT  = (unsigned short*)(ws + 55050240);    // 25165824
  unsigned short* vN  = (unsigned short*)(ws + 80216064);    // 25165824
  float* nq           = (float*)(ws + 105381888);            // 49152
  float* nk           = (float*)(ws + 105431040);            // 49152
  unsigned short* P   = (unsigned short*)(ws + 105480192);   // 2359296
  float* yp           = (float*)(ws + 29884416);             // aliases qT+kT (dead by then)
  unsigned short* xca = xb;                                  // aliases xb (dead by then)

  k_cvt<<<dim3(2048), dim3(256), 0, stream>>>(x, xb, 16384 * 768 / 4);
  k_cvt<<<dim3(1728), dim3(256), 0, stream>>>(wqkv, wqb, 2304 * 768 / 4);
  k_cvt<<<dim3(576), dim3(256), 0, stream>>>(wproj, wpb, 768 * 768 / 4);
  k_gemm1<<<dim3(768), dim3(512), 0, stream>>>(xb, wqb, qT, kT, vN);
  k_norms<<<dim3(128), dim3(256), 0, stream>>>(qT, kT, nq, nk);
  k_attn<<<dim3(128), dim3(256), 0, stream>>>(qT, kT, nq, nk, temp, P);
  k_pv<<<dim3(128, 8), dim3(256), 0, stream>>>(vN, P, xca);
  k_gemm2<<<dim3(6, 128), dim3(256), 0, stream>>>(xca, wpb, yp);
  k_final<<<dim3(4096), dim3(256), 0, stream>>>(yp, x, cw, gamma, beta, out);
}

// Round 6
// 234.768 us; speedup vs baseline: 1.3929x; 1.0768x over previous
//
#include <hip/hip_runtime.h>

#define DEVI __device__ __forceinline__

typedef __bf16 bf16x8 __attribute__((ext_vector_type(8)));
typedef float f32x4 __attribute__((ext_vector_type(4)));

// ---------- small helpers ----------
DEVI unsigned short f2bf(float f) {
  unsigned u = __builtin_bit_cast(unsigned, f);
  u += 0x7FFFu + ((u >> 16) & 1u);   // RNE
  return (unsigned short)(u >> 16);
}
DEVI float bf2f(unsigned short s) {
  return __builtin_bit_cast(float, ((unsigned)s) << 16);
}
DEVI f32x4 mfma16(bf16x8 a, bf16x8 b, f32x4 c) {
  return __builtin_amdgcn_mfma_f32_16x16x32_bf16(a, b, c, 0, 0, 0);
}
DEVI void gload16(const void* g, void* l) {
  __builtin_amdgcn_global_load_lds(
      (const __attribute__((address_space(1))) void*)g,
      (__attribute__((address_space(3))) void*)l, 16, 0, 0);
}
// LDS fragment read, rows ROWB bytes, XOR-swizzle byte ^= (row&7)<<4
template <int ROWB>
DEVI bf16x8 frag_ld(const char* lds, int row, int kb) {
  int off = row * ROWB + (kb ^ ((row & 7) << 4));
  return __builtin_bit_cast(bf16x8, *(const uint4*)(lds + off));
}

// ---------- fp32 -> bf16 convert ----------
__global__ __launch_bounds__(256) void k_cvt(const float* __restrict__ in,
                                             unsigned short* __restrict__ out, int n4) {
  int i = blockIdx.x * 256 + threadIdx.x;
  int st = gridDim.x * 256;
  for (; i < n4; i += st) {
    float4 f = ((const float4*)in)[i];
    ushort4 o;
    o.x = f2bf(f.x); o.y = f2bf(f.y); o.z = f2bf(f.z); o.w = f2bf(f.w);
    ((ushort4*)out)[i] = o;
  }
}

// ---------- pipelined 256x192 GEMM (BK=64, 8 waves 2Mx4N, counted vmcnt) ----------
// MODE 0: qkv = x@wqkv^T, grid 768 (64mt x 12jt), scatter epilogue -> qT,kT,vP
// MODE 1: yp  = vP@B_b^T, grid 256 (64mt x 4jt), plain bf16 epilogue -> yp
// Half-tile issue order per K-tile: Ah0,Bh0,Bh1,Ah1 (2/2/1/2 loads per thread).
// Swizzle: LDS[row][cb ^ ((row&7)<<4)] = global[row][cb].
template <int MODE>
__global__ __launch_bounds__(512, 2) void k_gemm(const unsigned short* __restrict__ A,
                                                 const unsigned short* __restrict__ B0,
                                                 unsigned short* __restrict__ o0,
                                                 unsigned short* __restrict__ o1,
                                                 unsigned short* __restrict__ o2) {
  __shared__ alignas(16) char lds[114688];  // 2 bufs x (A 32KB + B 24KB)
  const int tid = threadIdx.x, l = tid & 63, wid = tid >> 6;
  const int wr = wid >> 2, wc = wid & 3;
  const int xg = blockIdx.x;
  const int CPX = MODE ? 32 : 96;             // blocks per XCD (bijective swizzle)
  const int NJT = MODE ? 4 : 12;
  const int li = (xg & 7) * CPX + (xg >> 3);
  const int jt = li % NJT, mt = li / NJT;
  const int m0 = mt * 256, j0 = jt * 192;
  const unsigned short* Bb = MODE ? B0 + (size_t)(m0 >> 10) * 589824 : B0;

  const unsigned short* srcg[4][2];
  int ldso[4][2];
#pragma unroll
  for (int ht = 0; ht < 4; ++ht) {
    const bool isA = (ht == 0) || (ht == 3);
#pragma unroll
    for (int i = 0; i < 2; ++i) {
      const int c = (ht == 2) ? wid : (2 * wid + i);
      int r0;
      if (ht == 0)      r0 = 8 * c + ((c & 8) << 3);
      else if (ht == 3) r0 = 64 + 8 * c + ((c & 8) << 3);
      else if (ht == 1) r0 = (c >> 2) * 48 + (c & 3) * 8;
      else              r0 = (c >> 1) * 48 + 32 + (c & 1) * 8;
      const int r = r0 + (l >> 3);
      const int scol = ((l & 7) ^ (l >> 3)) << 3;  // pre-swizzled source col (elems)
      srcg[ht][i] = (isA ? A + (size_t)(m0 + r) * 768 : Bb + (size_t)(j0 + r) * 768) + scol;
      ldso[ht][i] = (isA ? 0 : 32768) + r0 * 128;
    }
  }
  // fragment read columns: full XOR incl. bit 6 (k-slice bit)
  const int swz = (l & 7) << 4;
  const int uu = (l >> 4) << 4;
  const int c0 = uu ^ swz;
  const int c1 = (64 | uu) ^ swz;
  const int arow = (wr * 128 + (l & 15)) * 128;
  const int brow = 32768 + (wc * 48 + (l & 15)) * 128;

  f32x4 acc[8][3];
#pragma unroll
  for (int i = 0; i < 8; ++i)
#pragma unroll
    for (int j = 0; j < 3; ++j)
#pragma unroll
      for (int e = 0; e < 4; ++e) acc[i][j][e] = 0.f;
  bf16x8 a[4][2], b[3][2];

#define STAGE2(ht, nxt, ko)                                         \
  do {                                                              \
    gload16(srcg[ht][0] + (ko), lds + (nxt)*57344 + ldso[ht][0]);   \
    gload16(srcg[ht][1] + (ko), lds + (nxt)*57344 + ldso[ht][1]);   \
  } while (0)
#define STAGE1(ht, nxt, ko)                                         \
  gload16(srcg[ht][0] + (ko), lds + (nxt)*57344 + ldso[ht][0])
#define LD128(off) __builtin_bit_cast(bf16x8, *(const uint4*)(cb_ + (off)))

  STAGE2(0, 0, 0); STAGE2(1, 0, 0); STAGE1(2, 0, 0); STAGE2(3, 0, 0);
  asm volatile("s_waitcnt vmcnt(3)" ::: "memory");
  __builtin_amdgcn_s_barrier();

#define KBODY(KT, LASTF)                                                              \
  {                                                                                   \
    const char* cb_ = lds + ((KT) & 1) * 57344;                                       \
    const int nxt = (((KT) & 1) ^ 1);                                                 \
    const int ko = ((KT) + 1) * 64;                                                   \
    _Pragma("unroll") for (int mf = 0; mf < 4; ++mf) {                                \
      a[mf][0] = LD128(arow + mf * 2048 + c0);                                        \
      a[mf][1] = LD128(arow + mf * 2048 + c1);                                        \
    }                                                                                 \
    _Pragma("unroll") for (int nf = 0; nf < 2; ++nf) {                                \
      b[nf][0] = LD128(brow + nf * 2048 + c0);                                        \
      b[nf][1] = LD128(brow + nf * 2048 + c1);                                        \
    }                                                                                 \
    if (!(LASTF)) { STAGE2(0, nxt, ko); asm volatile("s_waitcnt vmcnt(4)" ::: "memory"); } \
    else          { asm volatile("s_waitcnt vmcnt(2)" ::: "memory"); }                \
    __builtin_amdgcn_s_barrier();                                                     \
    __builtin_amdgcn_s_setprio(1);                                                    \
    _Pragma("unroll") for (int mf = 0; mf < 4; ++mf)                                  \
      _Pragma("unroll") for (int nf = 0; nf < 2; ++nf) {                              \
        acc[mf][nf] = mfma16(a[mf][0], b[nf][0], acc[mf][nf]);                        \
        acc[mf][nf] = mfma16(a[mf][1], b[nf][1], acc[mf][nf]);                        \
      }                                                                               \
    __builtin_amdgcn_s_setprio(0);                                                    \
    b[2][0] = LD128(brow + 2 * 2048 + c0);                                            \
    b[2][1] = LD128(brow + 2 * 2048 + c1);                                            \
    if (!(LASTF)) { STAGE2(1, nxt, ko); asm volatile("s_waitcnt vmcnt(4)" ::: "memory"); } \
    else          { asm volatile("s_waitcnt vmcnt(0)" ::: "memory"); }                \
    __builtin_amdgcn_s_barrier();                                                     \
    __builtin_amdgcn_s_setprio(1);                                                    \
    _Pragma("unroll") for (int mf = 0; mf < 4; ++mf) {                                \
      acc[mf][2] = mfma16(a[mf][0], b[2][0], acc[mf][2]);                             \
      acc[mf][2] = mfma16(a[mf][1], b[2][1], acc[mf][2]);                             \
    }                                                                                 \
    __builtin_amdgcn_s_setprio(0);                                                    \
    _Pragma("unroll") for (int mf = 0; mf < 4; ++mf) {                                \
      a[mf][0] = LD128(arow + (mf + 4) * 2048 + c0);                                  \
      a[mf][1] = LD128(arow + (mf + 4) * 2048 + c1);                                  \
    }                                                                                 \
    if (!(LASTF)) STAGE1(2, nxt, ko);                                                 \
    asm volatile("" ::: "memory");                                                    \
    __builtin_amdgcn_s_barrier();                                                     \
    __builtin_amdgcn_s_setprio(1);                                                    \
    _Pragma("unroll") for (int mf = 0; mf < 4; ++mf)                                  \
      _Pragma("unroll") for (int nf = 0; nf < 2; ++nf) {                              \
        acc[mf + 4][nf] = mfma16(a[mf][0], b[nf][0], acc[mf + 4][nf]);                \
        acc[mf + 4][nf] = mfma16(a[mf][1], b[nf][1], acc[mf + 4][nf]);                \
      }                                                                               \
    __builtin_amdgcn_s_setprio(0);                                                    \
    if (!(LASTF)) { STAGE2(3, nxt, ko); asm volatile("s_waitcnt vmcnt(3)" ::: "memory"); } \
    else          { asm volatile("" ::: "memory"); }                                  \
    __builtin_amdgcn_s_barrier();                                                     \
    __builtin_amdgcn_s_setprio(1);                                                    \
    _Pragma("unroll") for (int mf = 0; mf < 4; ++mf) {                                \
      acc[mf + 4][2] = mfma16(a[mf][0], b[2][0], acc[mf + 4][2]);                     \
      acc[mf + 4][2] = mfma16(a[mf][1], b[2][1], acc[mf + 4][2]);                     \
    }                                                                                 \
    __builtin_amdgcn_s_setprio(0);                                                    \
  }

#pragma unroll 1
  for (int kt = 0; kt < 11; ++kt) KBODY(kt, false);
  KBODY(11, true);
#undef KBODY
#undef STAGE2
#undef STAGE1
#undef LD128

  if constexpr (MODE == 0) {
    // scatter: jt 0-3 -> qT, 4-7 -> kT (transposed [bh][d][n]), 8-11 -> vP [n][768]
    const int s = j0 / 768;
    const int jin0 = (j0 % 768) + wc * 48 + (l & 15);
    const int ntok0 = m0 + wr * 128 + ((l >> 4) << 2);
#pragma unroll
    for (int mf = 0; mf < 8; ++mf) {
      const int nt = ntok0 + mf * 16;
      const int bb = nt >> 10, nin = nt & 1023;
#pragma unroll
      for (int nf = 0; nf < 3; ++nf) {
        const int jj = jin0 + nf * 16;
        const int hh = jj / 96, dd = jj % 96;
        if (s == 2) {
          unsigned short* vp = o2 + (size_t)nt * 768 + jj;
#pragma unroll
          for (int rr = 0; rr < 4; ++rr) vp[rr * 768] = f2bf(acc[mf][nf][rr]);
        } else {
          unsigned short* base = (s == 0) ? o0 : o1;
          ushort4 pk;
          pk.x = f2bf(acc[mf][nf][0]); pk.y = f2bf(acc[mf][nf][1]);
          pk.z = f2bf(acc[mf][nf][2]); pk.w = f2bf(acc[mf][nf][3]);
          *(ushort4*)(base + ((size_t)((bb * 8 + hh) * 96 + dd)) * 1024 + nin) = pk;
        }
      }
    }
  } else {
    const int ntok0 = m0 + wr * 128 + ((l >> 4) << 2);
    const int col0 = j0 + wc * 48 + (l & 15);
#pragma unroll
    for (int mf = 0; mf < 8; ++mf)
#pragma unroll
      for (int nf = 0; nf < 3; ++nf) {
        unsigned short* yp = o0 + (size_t)(ntok0 + mf * 16) * 768 + col0 + nf * 16;
#pragma unroll
        for (int rr = 0; rr < 4; ++rr) yp[rr * 768] = f2bf(acc[mf][nf][rr]);
      }
  }
}

// ---------- A' = q^T k; scale 1/(|q||k|temp); softmax; write P^T ----------
// Norms computed inline (reads qT/kT rows once extra; L2-resident for staging).
DEVI float ssq8(uint4 u) {
  unsigned a[4] = {u.x, u.y, u.z, u.w};
  float s = 0.f;
#pragma unroll
  for (int i = 0; i < 4; ++i) {
    float lo = __builtin_bit_cast(float, a[i] << 16);
    float hi = __builtin_bit_cast(float, a[i] & 0xFFFF0000u);
    s += lo * lo + hi * hi;
  }
  return s;
}

__global__ __launch_bounds__(256) void k_attn(const unsigned short* __restrict__ qT,
                                              const unsigned short* __restrict__ kT,
                                              const float* __restrict__ temp,
                                              unsigned short* __restrict__ PT) {
  __shared__ alignas(16) char lQ[12288];   // [96][64] bf16 swizzled
  __shared__ alignas(16) char lK[12288];
  __shared__ float lA[96 * 96];
  __shared__ float lrq[96], lrk[96];
  const int bh = blockIdx.x, tid = threadIdx.x, lane = tid & 63, wid = tid >> 6;
  const float invt = 1.f / temp[bh & 7];
  const int wr = wid >> 1, wc = wid & 1;
  const unsigned short* qb = qT + (size_t)bh * 96 * 1024;
  const unsigned short* kb = kT + (size_t)bh * 96 * 1024;

  // inline token-dim norms: 192 rows across 4 waves
  for (int row = wid; row < 192; row += 4) {
    const unsigned short* src = (row < 96) ? qb + (size_t)row * 1024
                                           : kb + (size_t)(row - 96) * 1024;
    const uint4* p = (const uint4*)src + lane * 2;
    float s = ssq8(p[0]) + ssq8(p[1]);
#pragma unroll
    for (int off = 32; off; off >>= 1) s += __shfl_xor(s, off, 64);
    if (lane == 0) {
      float r = 1.f / fmaxf(sqrtf(s), 1e-12f);
      if (row < 96) lrq[row] = r;
      else          lrk[row - 96] = r;
    }
  }

  const unsigned short* srcp[6];
  char* dstp[6];
#pragma unroll
  for (int i = 0; i < 6; ++i) {
    int cid = wid * 6 + i;          // 24 chunks: 12 q + 12 k
    bool isK = cid >= 12;
    int c = isK ? cid - 12 : cid;
    int p = c * 1024 + lane * 16;
    int r = p >> 7, cb = p & 127;
    int cbs = cb ^ ((r & 7) << 4);
    srcp[i] = (isK ? kb : qb) + (size_t)r * 1024 + (cbs >> 1);
    dstp[i] = (isK ? lK : lQ) + c * 1024;
  }

  f32x4 acc[3][3];
#pragma unroll
  for (int i = 0; i < 3; ++i)
#pragma unroll
    for (int j = 0; j < 3; ++j)
#pragma unroll
      for (int e = 0; e < 4; ++e) acc[i][j][e] = 0.f;

  for (int k0 = 0; k0 < 1024; k0 += 64) {
    __syncthreads();
#pragma unroll
    for (int i = 0; i < 6; ++i) gload16(srcp[i] + k0, dstp[i]);
    __syncthreads();
#pragma unroll
    for (int ks = 0; ks < 2; ++ks) {
      const int kb2 = ks * 64 + ((lane >> 4) << 4);
      bf16x8 af[3], bfv[3];
#pragma unroll
      for (int mb = 0; mb < 3; ++mb) af[mb] = frag_ld<128>(lQ, wr * 48 + mb * 16 + (lane & 15), kb2);
#pragma unroll
      for (int nb = 0; nb < 3; ++nb) bfv[nb] = frag_ld<128>(lK, wc * 48 + nb * 16 + (lane & 15), kb2);
#pragma unroll
      for (int mb = 0; mb < 3; ++mb)
#pragma unroll
        for (int nb = 0; nb < 3; ++nb) acc[mb][nb] = mfma16(af[mb], bfv[nb], acc[mb][nb]);
    }
  }

  const int rb = wr * 48 + ((lane >> 4) << 2);
  const int eb = wc * 48 + (lane & 15);
#pragma unroll
  for (int mb = 0; mb < 3; ++mb)
#pragma unroll
    for (int nb = 0; nb < 3; ++nb) {
      int e = eb + nb * 16;
#pragma unroll
      for (int rr = 0; rr < 4; ++rr) {
        int d = rb + mb * 16 + rr;
        lA[d * 96 + e] = acc[mb][nb][rr] * lrq[d] * lrk[e] * invt;
      }
    }
  __syncthreads();
  for (int d = wid; d < 96; d += 4) {
    float v0 = lA[d * 96 + lane];
    float v1 = (lane < 32) ? lA[d * 96 + 64 + lane] : -3.0e38f;
    float mx = fmaxf(v0, v1);
#pragma unroll
    for (int off = 32; off; off >>= 1) mx = fmaxf(mx, __shfl_xor(mx, off, 64));
    float p0 = __expf(v0 - mx);
    float p1 = (lane < 32) ? __expf(v1 - mx) : 0.f;
    float ssum = p0 + p1;
#pragma unroll
    for (int off = 32; off; off >>= 1) ssum += __shfl_xor(ssum, off, 64);
    float rs = 1.f / ssum;
    // write transposed: PT[bh][e][d]
    PT[((size_t)bh * 96 + lane) * 96 + d] = f2bf(p0 * rs);
    if (lane < 32) PT[((size_t)bh * 96 + 64 + lane) * 96 + d] = f2bf(p1 * rs);
  }
}

// ---------- B_b[(h,e), c] pre-contraction: B_h = P_h^T @ W_h^T ----------
// B_all[b][c][h*96+e] = sum_d PT[bh][e][d] * wproj[c][h*96+d]
// grid: b(16) x h(8) x cq(4); block 256 = 4 waves (2x2), tile [96 e][192 c], K=96.
__global__ __launch_bounds__(256) void k_prep(const unsigned short* __restrict__ PT,
                                              const float* __restrict__ wproj,
                                              unsigned short* __restrict__ B_all) {
  __shared__ alignas(16) unsigned short lPt[96 * 104];   // pad 96->104 (bank spread)
  __shared__ alignas(16) unsigned short lW[192 * 104];
  const int blk = blockIdx.x;
  const int b = blk >> 5, h = (blk >> 2) & 7, cq = blk & 3;
  const int tid = threadIdx.x, l = tid & 63, wid = tid >> 6;
  const int wr = wid >> 1, wc = wid & 1;

  const unsigned short* pt = PT + (size_t)(b * 8 + h) * 96 * 96;
  for (int idx = tid; idx < 1152; idx += 256) {   // 96 rows x 12 chunks of 8
    int r = idx / 12, ch = idx % 12;
    *(uint4*)(lPt + r * 104 + ch * 8) = *(const uint4*)(pt + r * 96 + ch * 8);
  }
  for (int idx = tid; idx < 4608; idx += 256) {   // 192 rows x 24 chunks of 4 (fp32->bf16)
    int r = idx / 24, ch = idx % 24;
    float4 f = *(const float4*)(wproj + (size_t)(cq * 192 + r) * 768 + h * 96 + ch * 4);
    ushort4 o;
    o.x = f2bf(f.x); o.y = f2bf(f.y); o.z = f2bf(f.z); o.w = f2bf(f.w);
    *(ushort4*)(lW + r * 104 + ch * 4) = o;
  }
  __syncthreads();

  f32x4 acc[3][6];
#pragma unroll
  for (int i = 0; i < 3; ++i)
#pragma unroll
    for (int j = 0; j < 6; ++j)
#pragma unroll
      for (int e = 0; e < 4; ++e) acc[i][j][e] = 0.f;

#pragma unroll
  for (int ks = 0; ks < 3; ++ks) {
    const int kof = ks * 32 + ((l >> 4) << 3);
    bf16x8 af[3], bv[6];
#pragma unroll
    for (int mb = 0; mb < 3; ++mb)
      af[mb] = __builtin_bit_cast(bf16x8, *(const uint4*)(lPt + (wr * 48 + mb * 16 + (l & 15)) * 104 + kof));
#pragma unroll
    for (int nb = 0; nb < 6; ++nb)
      bv[nb] = __builtin_bit_cast(bf16x8, *(const uint4*)(lW + (wc * 96 + nb * 16 + (l & 15)) * 104 + kof));
#pragma unroll
    for (int mb = 0; mb < 3; ++mb)
#pragma unroll
      for (int nb = 0; nb < 6; ++nb) acc[mb][nb] = mfma16(af[mb], bv[nb], acc[mb][nb]);
  }

  const int e0 = wr * 48 + ((l >> 4) << 2);
  const int c0 = cq * 192 + wc * 96 + (l & 15);
#pragma unroll
  for (int mb = 0; mb < 3; ++mb)
#pragma unroll
    for (int nb = 0; nb < 6; ++nb) {
      ushort4 pk;
      pk.x = f2bf(acc[mb][nb][0]); pk.y = f2bf(acc[mb][nb][1]);
      pk.z = f2bf(acc[mb][nb][2]); pk.w = f2bf(acc[mb][nb][3]);
      *(ushort4*)(B_all + ((size_t)(b * 768) + c0 + nb * 16) * 768 + h * 96 + e0 + mb * 16) = pk;
    }
}

// ---------- final: y = yp(bf16) + 0.1*dwconv3x3(x); LayerNorm ----------
__global__ __launch_bounds__(256) void k_final(const unsigned short* __restrict__ yp,
                                               const float* __restrict__ x,
                                               const float* __restrict__ cw,
                                               const float* __restrict__ gamma,
                                               const float* __restrict__ beta,
                                               float* __restrict__ out) {
  const int wid = threadIdx.x >> 6, lane = threadIdx.x & 63;
  const int m = blockIdx.x * 4 + wid;           // token id
  const int bb = m >> 10, n = m & 1023, yy = n >> 5, xx = n & 31;
  const float* xb = x + (size_t)bb * 1024 * 768;

  float yv[3][4];
#pragma unroll
  for (int g = 0; g < 3; ++g) {
    const int c = g * 256 + lane * 4;
    float w36[36];
    const float4* wp = (const float4*)(cw + (size_t)c * 9);
#pragma unroll
    for (int i = 0; i < 9; ++i) *(float4*)(w36 + i * 4) = wp[i];

    float a0 = 0.f, a1 = 0.f, a2 = 0.f, a3 = 0.f;
#pragma unroll
    for (int dy = -1; dy <= 1; ++dy) {
      int ny = yy + dy;
      if ((unsigned)ny < 32u) {
#pragma unroll
        for (int dx = -1; dx <= 1; ++dx) {
          int nx = xx + dx;
          if ((unsigned)nx < 32u) {
            float4 v = *(const float4*)(xb + (size_t)(ny * 32 + nx) * 768 + c);
            const int j = (dy + 1) * 3 + (dx + 1);
            a0 += w36[0 * 9 + j] * v.x;
            a1 += w36[1 * 9 + j] * v.y;
            a2 += w36[2 * 9 + j] * v.z;
            a3 += w36[3 * 9 + j] * v.w;
          }
        }
      }
    }
    ushort4 f = *(const ushort4*)(yp + (size_t)m * 768 + c);
    yv[g][0] = bf2f(f.x) + 0.1f * a0;
    yv[g][1] = bf2f(f.y) + 0.1f * a1;
    yv[g][2] = bf2f(f.z) + 0.1f * a2;
    yv[g][3] = bf2f(f.w) + 0.1f * a3;
  }

  float s1 = 0.f, s2 = 0.f;
#pragma unroll
  for (int g = 0; g < 3; ++g)
#pragma unroll
    for (int e = 0; e < 4; ++e) { s1 += yv[g][e]; s2 += yv[g][e] * yv[g][e]; }
#pragma unroll
  for (int off = 32; off; off >>= 1) {
    s1 += __shfl_xor(s1, off, 64);
    s2 += __shfl_xor(s2, off, 64);
  }
  const float mu = s1 * (1.f / 768.f);
  const float var = s2 * (1.f / 768.f) - mu * mu;
  const float rs = rsqrtf(var + 1e-5f);

#pragma unroll
  for (int g = 0; g < 3; ++g) {
    const int c = g * 256 + lane * 4;
    float4 gm = *(const float4*)(gamma + c);
    float4 bt = *(const float4*)(beta + c);
    float4 o;
    o.x = (yv[g][0] - mu) * rs * gm.x + bt.x;
    o.y = (yv[g][1] - mu) * rs * gm.y + bt.y;
    o.z = (yv[g][2] - mu) * rs * gm.z + bt.z;
    o.w = (yv[g][3] - mu) * rs * gm.w + bt.w;
    *(float4*)(out + (size_t)m * 768 + c) = o;
  }
}

// ---------- host ----------
extern "C" void kernel_launch(void* const* d_in, const int* in_sizes, int n_in,
                              void* d_out, int out_size, void* d_ws, size_t ws_size,
                              hipStream_t stream) {
  const float* x     = (const float*)d_in[0];
  const float* wqkv  = (const float*)d_in[1];
  const float* wproj = (const float*)d_in[2];
  const float* temp  = (const float*)d_in[3];
  const float* cw    = (const float*)d_in[4];
  const float* gamma = (const float*)d_in[5];
  const float* beta  = (const float*)d_in[6];
  float* out = (float*)d_out;
  char* ws = (char*)d_ws;

  // workspace layout (~107 MiB; aliased regions are stream-ordered dead)
  unsigned short* xb    = (unsigned short*)(ws);               // 25165824 B (x bf16; dead after gemm1)
  unsigned short* B_all = xb;                                  //   alias: 16*768*768*2 = 18874368 B
  unsigned short* wqb   = (unsigned short*)(ws + 25165824);    // 3538944
  unsigned short* qT    = (unsigned short*)(ws + 28704768);    // 25165824 (dead after attn)
  unsigned short* yp    = qT;                                  //   alias: 25165824
  unsigned short* kT    = (unsigned short*)(ws + 53870592);    // 25165824
  unsigned short* vP    = (unsigned short*)(ws + 79036416);    // 25165824
  unsigned short* PT    = (unsigned short*)(ws + 104202240);   // 2359296

  k_cvt<<<dim3(2048), dim3(256), 0, stream>>>(x, xb, 16384 * 768 / 4);
  k_cvt<<<dim3(1728), dim3(256), 0, stream>>>(wqkv, wqb, 2304 * 768 / 4);
  k_gemm<0><<<dim3(768), dim3(512), 0, stream>>>(xb, wqb, qT, kT, vP);
  k_attn<<<dim3(128), dim3(256), 0, stream>>>(qT, kT, temp, PT);
  k_prep<<<dim3(512), dim3(256), 0, stream>>>(PT, wproj, B_all);
  k_gemm<1><<<dim3(256), dim3(512), 0, stream>>>(vP, B_all, yp, nullptr, nullptr);
  k_final<<<dim3(4096), dim3(256), 0, stream>>>(yp, x, cw, gamma, beta, out);
}

// Round 7
// 231.785 us; speedup vs baseline: 1.4109x; 1.0129x over previous
//
#include <hip/hip_runtime.h>

#define DEVI __device__ __forceinline__

typedef __bf16 bf16x8 __attribute__((ext_vector_type(8)));
typedef float f32x4 __attribute__((ext_vector_type(4)));

// ---------- small helpers ----------
DEVI unsigned short f2bf(float f) {
  unsigned u = __builtin_bit_cast(unsigned, f);
  u += 0x7FFFu + ((u >> 16) & 1u);   // RNE
  return (unsigned short)(u >> 16);
}
DEVI float bf2f(unsigned short s) {
  return __builtin_bit_cast(float, ((unsigned)s) << 16);
}
DEVI f32x4 mfma16(bf16x8 a, bf16x8 b, f32x4 c) {
  return __builtin_amdgcn_mfma_f32_16x16x32_bf16(a, b, c, 0, 0, 0);
}
DEVI void gload16(const void* g, void* l) {
  __builtin_amdgcn_global_load_lds(
      (const __attribute__((address_space(1))) void*)g,
      (__attribute__((address_space(3))) void*)l, 16, 0, 0);
}
// LDS fragment read, rows ROWB bytes, XOR-swizzle byte ^= (row&7)<<4
template <int ROWB>
DEVI bf16x8 frag_ld(const char* lds, int row, int kb) {
  int off = row * ROWB + (kb ^ ((row & 7) << 4));
  return __builtin_bit_cast(bf16x8, *(const uint4*)(lds + off));
}

// ---------- fp32 -> bf16 convert ----------
__global__ __launch_bounds__(256) void k_cvt(const float* __restrict__ in,
                                             unsigned short* __restrict__ out, int n4) {
  int i = blockIdx.x * 256 + threadIdx.x;
  int st = gridDim.x * 256;
  for (; i < n4; i += st) {
    float4 f = ((const float4*)in)[i];
    ushort4 o;
    o.x = f2bf(f.x); o.y = f2bf(f.y); o.z = f2bf(f.z); o.w = f2bf(f.w);
    ((ushort4*)out)[i] = o;
  }
}

// ---------- pipelined 128x192 GEMM (BK=64, 8 waves 2Mx4N, 2 blocks/CU) ----------
// MODE 0: qkv = x@wqkv^T, grid 1536 (128mt x 12jt = 3 exact rounds), scatter -> qT,kT,vP
// MODE 1: yp  = vP@B_b^T, grid 512 (128mt x 4jt = 1 exact round), bf16 -> yp
// LDS 80KB (2 bufs x (A 16KB + B 24KB)) -> 2 blocks/CU, 4 waves/SIMD.
// Stage groups per K-tile (per-thread loads): S0=A rows{0-31,64-95} (1),
//   S1=B rows{wc*48+[0,32)} (2), S2=B rows{wc*48+[32,48)} (1), S3=A rows{32-63,96-127} (1).
// Phases: ph0 reads S0+S1, MFMA mf01xnf01; ph1 reads S2, MFMA mf01xnf2;
//         ph2 reads S3, MFMA mf23xnf01; ph3 MFMA mf23xnf2.
// Ledger (steady): ph0 stage S0' vmcnt(2); ph1 stage S1' vmcnt(3); ph2 stage S2' (no wait);
//                  ph3 stage S3' vmcnt(2). Last iter: vmcnt(1)/vmcnt(0)/-/-.
// Swizzle: LDS[row][cb ^ ((row&7)<<4)] = global[row][cb].
template <int MODE>
__global__ __launch_bounds__(512, 4) void k_gemm(const unsigned short* __restrict__ A,
                                                 const unsigned short* __restrict__ B0,
                                                 unsigned short* __restrict__ o0,
                                                 unsigned short* __restrict__ o1,
                                                 unsigned short* __restrict__ o2) {
  __shared__ alignas(16) char lds[81920];
  const int tid = threadIdx.x, l = tid & 63, wid = tid >> 6;
  const int wr = wid >> 2, wc = wid & 3;
  const int xg = blockIdx.x;
  const int CPX = MODE ? 64 : 192;            // blocks per XCD (bijective swizzle)
  const int NJT = MODE ? 4 : 12;
  const int li = (xg & 7) * CPX + (xg >> 3);
  const int jt = li % NJT, mt = li / NJT;
  const int m0 = mt * 128, j0 = jt * 192;
  const unsigned short* Bb = MODE ? B0 + (size_t)(m0 >> 10) * 589824 : B0;

  // staging sources; sg 0..3 = S0..S3 (S1 has 2 loads/thread)
  const unsigned short* srcg[4][2];
  int ldso[4][2];
#pragma unroll
  for (int sg = 0; sg < 4; ++sg) {
    const bool isA = (sg == 0) || (sg == 3);
#pragma unroll
    for (int i = 0; i < 2; ++i) {
      int c;
      if (sg == 0)      c = (wid < 4) ? wid : wid + 4;
      else if (sg == 3) c = (wid < 4) ? wid + 4 : wid + 8;
      else if (sg == 1) { int cc = 2 * wid + i; c = (cc >> 2) * 6 + (cc & 3); }
      else              c = (wid >> 1) * 6 + 4 + (wid & 1);
      const int r0 = 8 * c;
      const int r = r0 + (l >> 3);
      const int scol = ((l & 7) ^ (l >> 3)) << 3;  // pre-swizzled source col (elems)
      srcg[sg][i] = (isA ? A + (size_t)(m0 + r) * 768 : Bb + (size_t)(j0 + r) * 768) + scol;
      ldso[sg][i] = (isA ? 0 : 16384) + r0 * 128;
    }
  }
  // fragment read columns: full XOR incl. bit 6 (k-slice bit)
  const int swz = (l & 7) << 4;
  const int uu = (l >> 4) << 4;
  const int c0 = uu ^ swz;
  const int c1 = (64 | uu) ^ swz;
  const int arow = (wr * 64 + (l & 15)) * 128;
  const int brow = 16384 + (wc * 48 + (l & 15)) * 128;

  f32x4 acc[4][3];
#pragma unroll
  for (int i = 0; i < 4; ++i)
#pragma unroll
    for (int j = 0; j < 3; ++j)
#pragma unroll
      for (int e = 0; e < 4; ++e) acc[i][j][e] = 0.f;
  bf16x8 a[2][2], b01[2][2], b2[2];

#define STAGE1(sg, nxt, ko) \
  gload16(srcg[sg][0] + (ko), lds + (nxt)*40960 + ldso[sg][0])
#define STAGE2(sg, nxt, ko)                                        \
  do {                                                             \
    gload16(srcg[sg][0] + (ko), lds + (nxt)*40960 + ldso[sg][0]);  \
    gload16(srcg[sg][1] + (ko), lds + (nxt)*40960 + ldso[sg][1]);  \
  } while (0)
#define LD128(off) __builtin_bit_cast(bf16x8, *(const uint4*)(cb_ + (off)))

  // prologue: stage K-tile 0 (5 loads: S0,S1x2,S2,S3); land S0+S1, keep S2,S3 in flight
  STAGE1(0, 0, 0); STAGE2(1, 0, 0); STAGE1(2, 0, 0); STAGE1(3, 0, 0);
  asm volatile("s_waitcnt vmcnt(2)" ::: "memory");
  __builtin_amdgcn_s_barrier();

#define KBODY(KT, LASTF)                                                              \
  {                                                                                   \
    const char* cb_ = lds + ((KT) & 1) * 40960;                                       \
    const int nxt = (((KT) & 1) ^ 1);                                                 \
    const int ko = ((KT) + 1) * 64;                                                   \
    /* ph0: read A mf0-1 + B nf0-1, stage S0' */                                      \
    _Pragma("unroll") for (int mf = 0; mf < 2; ++mf) {                                \
      a[mf][0] = LD128(arow + mf * 2048 + c0);                                        \
      a[mf][1] = LD128(arow + mf * 2048 + c1);                                        \
    }                                                                                 \
    _Pragma("unroll") for (int nf = 0; nf < 2; ++nf) {                                \
      b01[nf][0] = LD128(brow + nf * 2048 + c0);                                      \
      b01[nf][1] = LD128(brow + nf * 2048 + c1);                                      \
    }                                                                                 \
    if (!(LASTF)) { STAGE1(0, nxt, ko); asm volatile("s_waitcnt vmcnt(2)" ::: "memory"); } \
    else          { asm volatile("s_waitcnt vmcnt(1)" ::: "memory"); }                \
    __builtin_amdgcn_s_barrier();                                                     \
    __builtin_amdgcn_s_setprio(1);                                                    \
    _Pragma("unroll") for (int mf = 0; mf < 2; ++mf)                                  \
      _Pragma("unroll") for (int nf = 0; nf < 2; ++nf) {                              \
        acc[mf][nf] = mfma16(a[mf][0], b01[nf][0], acc[mf][nf]);                      \
        acc[mf][nf] = mfma16(a[mf][1], b01[nf][1], acc[mf][nf]);                      \
      }                                                                               \
    __builtin_amdgcn_s_setprio(0);                                                    \
    /* ph1: read B nf2, stage S1' */                                                  \
    b2[0] = LD128(brow + 2 * 2048 + c0);                                              \
    b2[1] = LD128(brow + 2 * 2048 + c1);                                              \
    if (!(LASTF)) { STAGE2(1, nxt, ko); asm volatile("s_waitcnt vmcnt(3)" ::: "memory"); } \
    else          { asm volatile("s_waitcnt vmcnt(0)" ::: "memory"); }                \
    __builtin_amdgcn_s_barrier();                                                     \
    __builtin_amdgcn_s_setprio(1);                                                    \
    _Pragma("unroll") for (int mf = 0; mf < 2; ++mf) {                                \
      acc[mf][2] = mfma16(a[mf][0], b2[0], acc[mf][2]);                               \
      acc[mf][2] = mfma16(a[mf][1], b2[1], acc[mf][2]);                               \
    }                                                                                 \
    __builtin_amdgcn_s_setprio(0);                                                    \
    /* ph2: read A mf2-3, stage S2', no wait */                                       \
    _Pragma("unroll") for (int mf = 0; mf < 2; ++mf) {                                \
      a[mf][0] = LD128(arow + (mf + 2) * 2048 + c0);                                  \
      a[mf][1] = LD128(arow + (mf + 2) * 2048 + c1);                                  \
    }                                                                                 \
    if (!(LASTF)) STAGE1(2, nxt, ko);                                                 \
    asm volatile("" ::: "memory");                                                    \
    __builtin_amdgcn_s_barrier();                                                     \
    __builtin_amdgcn_s_setprio(1);                                                    \
    _Pragma("unroll") for (int mf = 0; mf < 2; ++mf)                                  \
      _Pragma("unroll") for (int nf = 0; nf < 2; ++nf) {                              \
        acc[mf + 2][nf] = mfma16(a[mf][0], b01[nf][0], acc[mf + 2][nf]);              \
        acc[mf + 2][nf] = mfma16(a[mf][1], b01[nf][1], acc[mf + 2][nf]);              \
      }                                                                               \
    __builtin_amdgcn_s_setprio(0);                                                    \
    /* ph3: stage S3', vmcnt(2) lands S0'+S1' */                                      \
    if (!(LASTF)) { STAGE1(3, nxt, ko); asm volatile("s_waitcnt vmcnt(2)" ::: "memory"); } \
    else          { asm volatile("" ::: "memory"); }                                  \
    __builtin_amdgcn_s_barrier();                                                     \
    __builtin_amdgcn_s_setprio(1);                                                    \
    _Pragma("unroll") for (int mf = 0; mf < 2; ++mf) {                                \
      acc[mf + 2][2] = mfma16(a[mf][0], b2[0], acc[mf + 2][2]);                       \
      acc[mf + 2][2] = mfma16(a[mf][1], b2[1], acc[mf + 2][2]);                       \
    }                                                                                 \
    __builtin_amdgcn_s_setprio(0);                                                    \
  }

#pragma unroll 1
  for (int kt = 0; kt < 11; ++kt) KBODY(kt, false);
  KBODY(11, true);
#undef KBODY
#undef STAGE2
#undef STAGE1
#undef LD128

  if constexpr (MODE == 0) {
    // scatter: jt 0-3 -> qT, 4-7 -> kT (transposed [bh][d][n]), 8-11 -> vP [n][768]
    const int s = j0 / 768;
    const int jin0 = (j0 % 768) + wc * 48 + (l & 15);
    const int ntok0 = m0 + wr * 64 + ((l >> 4) << 2);
#pragma unroll
    for (int mf = 0; mf < 4; ++mf) {
      const int nt = ntok0 + mf * 16;
      const int bb = nt >> 10, nin = nt & 1023;
#pragma unroll
      for (int nf = 0; nf < 3; ++nf) {
        const int jj = jin0 + nf * 16;
        const int hh = jj / 96, dd = jj % 96;
        if (s == 2) {
          unsigned short* vp = o2 + (size_t)nt * 768 + jj;
#pragma unroll
          for (int rr = 0; rr < 4; ++rr) vp[rr * 768] = f2bf(acc[mf][nf][rr]);
        } else {
          unsigned short* base = (s == 0) ? o0 : o1;
          ushort4 pk;
          pk.x = f2bf(acc[mf][nf][0]); pk.y = f2bf(acc[mf][nf][1]);
          pk.z = f2bf(acc[mf][nf][2]); pk.w = f2bf(acc[mf][nf][3]);
          *(ushort4*)(base + ((size_t)((bb * 8 + hh) * 96 + dd)) * 1024 + nin) = pk;
        }
      }
    }
  } else {
    const int ntok0 = m0 + wr * 64 + ((l >> 4) << 2);
    const int col0 = j0 + wc * 48 + (l & 15);
#pragma unroll
    for (int mf = 0; mf < 4; ++mf)
#pragma unroll
      for (int nf = 0; nf < 3; ++nf) {
        unsigned short* yp = o0 + (size_t)(ntok0 + mf * 16) * 768 + col0 + nf * 16;
#pragma unroll
        for (int rr = 0; rr < 4; ++rr) yp[rr * 768] = f2bf(acc[mf][nf][rr]);
      }
  }
}

// ---------- A' = q^T k; scale 1/(|q||k|temp); softmax; write P^T ----------
DEVI float ssq8(uint4 u) {
  unsigned a[4] = {u.x, u.y, u.z, u.w};
  float s = 0.f;
#pragma unroll
  for (int i = 0; i < 4; ++i) {
    float lo = __builtin_bit_cast(float, a[i] << 16);
    float hi = __builtin_bit_cast(float, a[i] & 0xFFFF0000u);
    s += lo * lo + hi * hi;
  }
  return s;
}

__global__ __launch_bounds__(256) void k_attn(const unsigned short* __restrict__ qT,
                                              const unsigned short* __restrict__ kT,
                                              const float* __restrict__ temp,
                                              unsigned short* __restrict__ PT) {
  __shared__ alignas(16) char lQ[12288];   // [96][64] bf16 swizzled
  __shared__ alignas(16) char lK[12288];
  __shared__ float lA[96 * 96];
  __shared__ float lrq[96], lrk[96];
  const int bh = blockIdx.x, tid = threadIdx.x, lane = tid & 63, wid = tid >> 6;
  const float invt = 1.f / temp[bh & 7];
  const int wr = wid >> 1, wc = wid & 1;
  const unsigned short* qb = qT + (size_t)bh * 96 * 1024;
  const unsigned short* kb = kT + (size_t)bh * 96 * 1024;

  // inline token-dim norms: 192 rows across 4 waves
  for (int row = wid; row < 192; row += 4) {
    const unsigned short* src = (row < 96) ? qb + (size_t)row * 1024
                                           : kb + (size_t)(row - 96) * 1024;
    const uint4* p = (const uint4*)src + lane * 2;
    float s = ssq8(p[0]) + ssq8(p[1]);
#pragma unroll
    for (int off = 32; off; off >>= 1) s += __shfl_xor(s, off, 64);
    if (lane == 0) {
      float r = 1.f / fmaxf(sqrtf(s), 1e-12f);
      if (row < 96) lrq[row] = r;
      else          lrk[row - 96] = r;
    }
  }

  const unsigned short* srcp[6];
  char* dstp[6];
#pragma unroll
  for (int i = 0; i < 6; ++i) {
    int cid = wid * 6 + i;          // 24 chunks: 12 q + 12 k
    bool isK = cid >= 12;
    int c = isK ? cid - 12 : cid;
    int p = c * 1024 + lane * 16;
    int r = p >> 7, cb = p & 127;
    int cbs = cb ^ ((r & 7) << 4);
    srcp[i] = (isK ? kb : qb) + (size_t)r * 1024 + (cbs >> 1);
    dstp[i] = (isK ? lK : lQ) + c * 1024;
  }

  f32x4 acc[3][3];
#pragma unroll
  for (int i = 0; i < 3; ++i)
#pragma unroll
    for (int j = 0; j < 3; ++j)
#pragma unroll
      for (int e = 0; e < 4; ++e) acc[i][j][e] = 0.f;

  for (int k0 = 0; k0 < 1024; k0 += 64) {
    __syncthreads();
#pragma unroll
    for (int i = 0; i < 6; ++i) gload16(srcp[i] + k0, dstp[i]);
    __syncthreads();
#pragma unroll
    for (int ks = 0; ks < 2; ++ks) {
      const int kb2 = ks * 64 + ((lane >> 4) << 4);
      bf16x8 af[3], bfv[3];
#pragma unroll
      for (int mb = 0; mb < 3; ++mb) af[mb] = frag_ld<128>(lQ, wr * 48 + mb * 16 + (lane & 15), kb2);
#pragma unroll
      for (int nb = 0; nb < 3; ++nb) bfv[nb] = frag_ld<128>(lK, wc * 48 + nb * 16 + (lane & 15), kb2);
#pragma unroll
      for (int mb = 0; mb < 3; ++mb)
#pragma unroll
        for (int nb = 0; nb < 3; ++nb) acc[mb][nb] = mfma16(af[mb], bfv[nb], acc[mb][nb]);
    }
  }

  const int rb = wr * 48 + ((lane >> 4) << 2);
  const int eb = wc * 48 + (lane & 15);
#pragma unroll
  for (int mb = 0; mb < 3; ++mb)
#pragma unroll
    for (int nb = 0; nb < 3; ++nb) {
      int e = eb + nb * 16;
#pragma unroll
      for (int rr = 0; rr < 4; ++rr) {
        int d = rb + mb * 16 + rr;
        lA[d * 96 + e] = acc[mb][nb][rr] * lrq[d] * lrk[e] * invt;
      }
    }
  __syncthreads();
  for (int d = wid; d < 96; d += 4) {
    float v0 = lA[d * 96 + lane];
    float v1 = (lane < 32) ? lA[d * 96 + 64 + lane] : -3.0e38f;
    float mx = fmaxf(v0, v1);
#pragma unroll
    for (int off = 32; off; off >>= 1) mx = fmaxf(mx, __shfl_xor(mx, off, 64));
    float p0 = __expf(v0 - mx);
    float p1 = (lane < 32) ? __expf(v1 - mx) : 0.f;
    float ssum = p0 + p1;
#pragma unroll
    for (int off = 32; off; off >>= 1) ssum += __shfl_xor(ssum, off, 64);
    float rs = 1.f / ssum;
    // write transposed: PT[bh][e][d]
    PT[((size_t)bh * 96 + lane) * 96 + d] = f2bf(p0 * rs);
    if (lane < 32) PT[((size_t)bh * 96 + 64 + lane) * 96 + d] = f2bf(p1 * rs);
  }
}

// ---------- B_b[(h,e), c] pre-contraction: B_h = P_h^T @ W_h^T ----------
__global__ __launch_bounds__(256) void k_prep(const unsigned short* __restrict__ PT,
                                              const float* __restrict__ wproj,
                                              unsigned short* __restrict__ B_all) {
  __shared__ alignas(16) unsigned short lPt[96 * 104];
  __shared__ alignas(16) unsigned short lW[192 * 104];
  const int blk = blockIdx.x;
  const int b = blk >> 5, h = (blk >> 2) & 7, cq = blk & 3;
  const int tid = threadIdx.x, l = tid & 63, wid = tid >> 6;
  const int wr = wid >> 1, wc = wid & 1;

  const unsigned short* pt = PT + (size_t)(b * 8 + h) * 96 * 96;
  for (int idx = tid; idx < 1152; idx += 256) {
    int r = idx / 12, ch = idx % 12;
    *(uint4*)(lPt + r * 104 + ch * 8) = *(const uint4*)(pt + r * 96 + ch * 8);
  }
  for (int idx = tid; idx < 4608; idx += 256) {
    int r = idx / 24, ch = idx % 24;
    float4 f = *(const float4*)(wproj + (size_t)(cq * 192 + r) * 768 + h * 96 + ch * 4);
    ushort4 o;
    o.x = f2bf(f.x); o.y = f2bf(f.y); o.z = f2bf(f.z); o.w = f2bf(f.w);
    *(ushort4*)(lW + r * 104 + ch * 4) = o;
  }
  __syncthreads();

  f32x4 acc[3][6];
#pragma unroll
  for (int i = 0; i < 3; ++i)
#pragma unroll
    for (int j = 0; j < 6; ++j)
#pragma unroll
      for (int e = 0; e < 4; ++e) acc[i][j][e] = 0.f;

#pragma unroll
  for (int ks = 0; ks < 3; ++ks) {
    const int kof = ks * 32 + ((l >> 4) << 3);
    bf16x8 af[3], bv[6];
#pragma unroll
    for (int mb = 0; mb < 3; ++mb)
      af[mb] = __builtin_bit_cast(bf16x8, *(const uint4*)(lPt + (wr * 48 + mb * 16 + (l & 15)) * 104 + kof));
#pragma unroll
    for (int nb = 0; nb < 6; ++nb)
      bv[nb] = __builtin_bit_cast(bf16x8, *(const uint4*)(lW + (wc * 96 + nb * 16 + (l & 15)) * 104 + kof));
#pragma unroll
    for (int mb = 0; mb < 3; ++mb)
#pragma unroll
      for (int nb = 0; nb < 6; ++nb) acc[mb][nb] = mfma16(af[mb], bv[nb], acc[mb][nb]);
  }

  const int e0 = wr * 48 + ((l >> 4) << 2);
  const int c0 = cq * 192 + wc * 96 + (l & 15);
#pragma unroll
  for (int mb = 0; mb < 3; ++mb)
#pragma unroll
    for (int nb = 0; nb < 6; ++nb) {
      ushort4 pk;
      pk.x = f2bf(acc[mb][nb][0]); pk.y = f2bf(acc[mb][nb][1]);
      pk.z = f2bf(acc[mb][nb][2]); pk.w = f2bf(acc[mb][nb][3]);
      *(ushort4*)(B_all + ((size_t)(b * 768) + c0 + nb * 16) * 768 + h * 96 + e0 + mb * 16) = pk;
    }
}

// ---------- final: y = yp(bf16) + 0.1*dwconv3x3(xb bf16); LayerNorm ----------
__global__ __launch_bounds__(256) void k_final(const unsigned short* __restrict__ yp,
                                               const unsigned short* __restrict__ xb16,
                                               const float* __restrict__ cw,
                                               const float* __restrict__ gamma,
                                               const float* __restrict__ beta,
                                               float* __restrict__ out) {
  const int wid = threadIdx.x >> 6, lane = threadIdx.x & 63;
  const int m = blockIdx.x * 4 + wid;           // token id
  const int bb = m >> 10, n = m & 1023, yy = n >> 5, xx = n & 31;
  const unsigned short* xb = xb16 + (size_t)bb * 1024 * 768;

  float yv[3][4];
#pragma unroll
  for (int g = 0; g < 3; ++g) {
    const int c = g * 256 + lane * 4;
    float w36[36];
    const float4* wp = (const float4*)(cw + (size_t)c * 9);
#pragma unroll
    for (int i = 0; i < 9; ++i) *(float4*)(w36 + i * 4) = wp[i];

    float a0 = 0.f, a1 = 0.f, a2 = 0.f, a3 = 0.f;
#pragma unroll
    for (int dy = -1; dy <= 1; ++dy) {
      int ny = yy + dy;
      if ((unsigned)ny < 32u) {
#pragma unroll
        for (int dx = -1; dx <= 1; ++dx) {
          int nx = xx + dx;
          if ((unsigned)nx < 32u) {
            ushort4 v = *(const ushort4*)(xb + (size_t)(ny * 32 + nx) * 768 + c);
            const int j = (dy + 1) * 3 + (dx + 1);
            a0 += w36[0 * 9 + j] * bf2f(v.x);
            a1 += w36[1 * 9 + j] * bf2f(v.y);
            a2 += w36[2 * 9 + j] * bf2f(v.z);
            a3 += w36[3 * 9 + j] * bf2f(v.w);
          }
        }
      }
    }
    ushort4 f = *(const ushort4*)(yp + (size_t)m * 768 + c);
    yv[g][0] = bf2f(f.x) + 0.1f * a0;
    yv[g][1] = bf2f(f.y) + 0.1f * a1;
    yv[g][2] = bf2f(f.z) + 0.1f * a2;
    yv[g][3] = bf2f(f.w) + 0.1f * a3;
  }

  float s1 = 0.f, s2 = 0.f;
#pragma unroll
  for (int g = 0; g < 3; ++g)
#pragma unroll
    for (int e = 0; e < 4; ++e) { s1 += yv[g][e]; s2 += yv[g][e] * yv[g][e]; }
#pragma unroll
  for (int off = 32; off; off >>= 1) {
    s1 += __shfl_xor(s1, off, 64);
    s2 += __shfl_xor(s2, off, 64);
  }
  const float mu = s1 * (1.f / 768.f);
  const float var = s2 * (1.f / 768.f) - mu * mu;
  const float rs = rsqrtf(var + 1e-5f);

#pragma unroll
  for (int g = 0; g < 3; ++g) {
    const int c = g * 256 + lane * 4;
    float4 gm = *(const float4*)(gamma + c);
    float4 bt = *(const float4*)(beta + c);
    float4 o;
    o.x = (yv[g][0] - mu) * rs * gm.x + bt.x;
    o.y = (yv[g][1] - mu) * rs * gm.y + bt.y;
    o.z = (yv[g][2] - mu) * rs * gm.z + bt.z;
    o.w = (yv[g][3] - mu) * rs * gm.w + bt.w;
    *(float4*)(out + (size_t)m * 768 + c) = o;
  }
}

// ---------- host ----------
extern "C" void kernel_launch(void* const* d_in, const int* in_sizes, int n_in,
                              void* d_out, int out_size, void* d_ws, size_t ws_size,
                              hipStream_t stream) {
  const float* x     = (const float*)d_in[0];
  const float* wqkv  = (const float*)d_in[1];
  const float* wproj = (const float*)d_in[2];
  const float* temp  = (const float*)d_in[3];
  const float* cw    = (const float*)d_in[4];
  const float* gamma = (const float*)d_in[5];
  const float* beta  = (const float*)d_in[6];
  float* out = (float*)d_out;
  char* ws = (char*)d_ws;

  // workspace layout (~107 MiB; aliased regions are stream-ordered dead)
  unsigned short* xb    = (unsigned short*)(ws);               // 25165824 B (x bf16; live to k_final)
  unsigned short* wqb   = (unsigned short*)(ws + 25165824);    // 3538944 (dead after gemm0)
  unsigned short* qT    = (unsigned short*)(ws + 28704768);    // 25165824 (dead after attn)
  unsigned short* yp    = qT;                                  //   alias
  unsigned short* kT    = (unsigned short*)(ws + 53870592);    // 25165824 (dead after attn)
  unsigned short* B_all = kT;                                  //   alias: 16*768*768*2 = 18874368
  unsigned short* vP    = (unsigned short*)(ws + 79036416);    // 25165824
  unsigned short* PT    = (unsigned short*)(ws + 104202240);   // 2359296

  k_cvt<<<dim3(2048), dim3(256), 0, stream>>>(x, xb, 16384 * 768 / 4);
  k_cvt<<<dim3(1728), dim3(256), 0, stream>>>(wqkv, wqb, 2304 * 768 / 4);
  k_gemm<0><<<dim3(1536), dim3(512), 0, stream>>>(xb, wqb, qT, kT, vP);
  k_attn<<<dim3(128), dim3(256), 0, stream>>>(qT, kT, temp, PT);
  k_prep<<<dim3(512), dim3(256), 0, stream>>>(PT, wproj, B_all);
  k_gemm<1><<<dim3(512), dim3(512), 0, stream>>>(vP, B_all, yp, nullptr, nullptr);
  k_final<<<dim3(4096), dim3(256), 0, stream>>>(yp, xb, cw, gamma, beta, out);
}

// Round 8
// 229.896 us; speedup vs baseline: 1.4225x; 1.0082x over previous
//
#include <hip/hip_runtime.h>

#define DEVI __device__ __forceinline__

typedef __bf16 bf16x8 __attribute__((ext_vector_type(8)));
typedef float f32x4 __attribute__((ext_vector_type(4)));

// ---------- small helpers ----------
DEVI unsigned short f2bf(float f) {
  unsigned u = __builtin_bit_cast(unsigned, f);
  u += 0x7FFFu + ((u >> 16) & 1u);   // RNE
  return (unsigned short)(u >> 16);
}
DEVI float bf2f(unsigned short s) {
  return __builtin_bit_cast(float, ((unsigned)s) << 16);
}
DEVI f32x4 mfma16(bf16x8 a, bf16x8 b, f32x4 c) {
  return __builtin_amdgcn_mfma_f32_16x16x32_bf16(a, b, c, 0, 0, 0);
}
DEVI void gload16(const void* g, void* l) {
  __builtin_amdgcn_global_load_lds(
      (const __attribute__((address_space(1))) void*)g,
      (__attribute__((address_space(3))) void*)l, 16, 0, 0);
}
// LDS fragment read, rows ROWB bytes, XOR-swizzle byte ^= (row&7)<<4
template <int ROWB>
DEVI bf16x8 frag_ld(const char* lds, int row, int kb) {
  int off = row * ROWB + (kb ^ ((row & 7) << 4));
  return __builtin_bit_cast(bf16x8, *(const uint4*)(lds + off));
}

// ---------- fp32 -> bf16 convert (x and wqkv in one launch) ----------
__global__ __launch_bounds__(256) void k_cvt2(const float* __restrict__ a,
                                              unsigned short* __restrict__ oa, int n4a,
                                              const float* __restrict__ b,
                                              unsigned short* __restrict__ ob, int n4b) {
  int i = blockIdx.x * 256 + threadIdx.x;
  int st = gridDim.x * 256;
  for (; i < n4a + n4b; i += st) {
    const float4* src = (i < n4a) ? ((const float4*)a) + i : ((const float4*)b) + (i - n4a);
    unsigned short* dst = (i < n4a) ? oa + 4 * (size_t)i : ob + 4 * (size_t)(i - n4a);
    float4 f = *src;
    ushort4 o;
    o.x = f2bf(f.x); o.y = f2bf(f.y); o.z = f2bf(f.z); o.w = f2bf(f.w);
    *(ushort4*)dst = o;
  }
}

// ---------- pipelined 128x192 GEMM (BK=64, 8 waves 2Mx4N, 2 blocks/CU) ----------
// MODE 0: qkv = x@wqkv^T, grid 1536 (128mt x 12jt = 3 exact rounds), scatter -> qT,kT,vP
// MODE 1: yp  = vP@B_b^T, grid 512 (128mt x 4jt = 1 exact round), bf16 -> yp
template <int MODE>
__global__ __launch_bounds__(512, 4) void k_gemm(const unsigned short* __restrict__ A,
                                                 const unsigned short* __restrict__ B0,
                                                 unsigned short* __restrict__ o0,
                                                 unsigned short* __restrict__ o1,
                                                 unsigned short* __restrict__ o2) {
  __shared__ alignas(16) char lds[81920];
  const int tid = threadIdx.x, l = tid & 63, wid = tid >> 6;
  const int wr = wid >> 2, wc = wid & 3;
  const int xg = blockIdx.x;
  const int CPX = MODE ? 64 : 192;            // blocks per XCD (bijective swizzle)
  const int NJT = MODE ? 4 : 12;
  const int li = (xg & 7) * CPX + (xg >> 3);
  const int jt = li % NJT, mt = li / NJT;
  const int m0 = mt * 128, j0 = jt * 192;
  const unsigned short* Bb = MODE ? B0 + (size_t)(m0 >> 10) * 589824 : B0;

  const unsigned short* srcg[4][2];
  int ldso[4][2];
#pragma unroll
  for (int sg = 0; sg < 4; ++sg) {
    const bool isA = (sg == 0) || (sg == 3);
#pragma unroll
    for (int i = 0; i < 2; ++i) {
      int c;
      if (sg == 0)      c = (wid < 4) ? wid : wid + 4;
      else if (sg == 3) c = (wid < 4) ? wid + 4 : wid + 8;
      else if (sg == 1) { int cc = 2 * wid + i; c = (cc >> 2) * 6 + (cc & 3); }
      else              c = (wid >> 1) * 6 + 4 + (wid & 1);
      const int r0 = 8 * c;
      const int r = r0 + (l >> 3);
      const int scol = ((l & 7) ^ (l >> 3)) << 3;
      srcg[sg][i] = (isA ? A + (size_t)(m0 + r) * 768 : Bb + (size_t)(j0 + r) * 768) + scol;
      ldso[sg][i] = (isA ? 0 : 16384) + r0 * 128;
    }
  }
  const int swz = (l & 7) << 4;
  const int uu = (l >> 4) << 4;
  const int c0 = uu ^ swz;
  const int c1 = (64 | uu) ^ swz;
  const int arow = (wr * 64 + (l & 15)) * 128;
  const int brow = 16384 + (wc * 48 + (l & 15)) * 128;

  f32x4 acc[4][3];
#pragma unroll
  for (int i = 0; i < 4; ++i)
#pragma unroll
    for (int j = 0; j < 3; ++j)
#pragma unroll
      for (int e = 0; e < 4; ++e) acc[i][j][e] = 0.f;
  bf16x8 a[2][2], b01[2][2], b2[2];

#define STAGE1(sg, nxt, ko) \
  gload16(srcg[sg][0] + (ko), lds + (nxt)*40960 + ldso[sg][0])
#define STAGE2(sg, nxt, ko)                                        \
  do {                                                             \
    gload16(srcg[sg][0] + (ko), lds + (nxt)*40960 + ldso[sg][0]);  \
    gload16(srcg[sg][1] + (ko), lds + (nxt)*40960 + ldso[sg][1]);  \
  } while (0)
#define LD128(off) __builtin_bit_cast(bf16x8, *(const uint4*)(cb_ + (off)))

  STAGE1(0, 0, 0); STAGE2(1, 0, 0); STAGE1(2, 0, 0); STAGE1(3, 0, 0);
  asm volatile("s_waitcnt vmcnt(2)" ::: "memory");
  __builtin_amdgcn_s_barrier();

#define KBODY(KT, LASTF)                                                              \
  {                                                                                   \
    const char* cb_ = lds + ((KT) & 1) * 40960;                                       \
    const int nxt = (((KT) & 1) ^ 1);                                                 \
    const int ko = ((KT) + 1) * 64;                                                   \
    _Pragma("unroll") for (int mf = 0; mf < 2; ++mf) {                                \
      a[mf][0] = LD128(arow + mf * 2048 + c0);                                        \
      a[mf][1] = LD128(arow + mf * 2048 + c1);                                        \
    }                                                                                 \
    _Pragma("unroll") for (int nf = 0; nf < 2; ++nf) {                                \
      b01[nf][0] = LD128(brow + nf * 2048 + c0);                                      \
      b01[nf][1] = LD128(brow + nf * 2048 + c1);                                      \
    }                                                                                 \
    if (!(LASTF)) { STAGE1(0, nxt, ko); asm volatile("s_waitcnt vmcnt(2)" ::: "memory"); } \
    else          { asm volatile("s_waitcnt vmcnt(1)" ::: "memory"); }                \
    __builtin_amdgcn_s_barrier();                                                     \
    __builtin_amdgcn_s_setprio(1);                                                    \
    _Pragma("unroll") for (int mf = 0; mf < 2; ++mf)                                  \
      _Pragma("unroll") for (int nf = 0; nf < 2; ++nf) {                              \
        acc[mf][nf] = mfma16(a[mf][0], b01[nf][0], acc[mf][nf]);                      \
        acc[mf][nf] = mfma16(a[mf][1], b01[nf][1], acc[mf][nf]);                      \
      }                                                                               \
    __builtin_amdgcn_s_setprio(0);                                                    \
    b2[0] = LD128(brow + 2 * 2048 + c0);                                              \
    b2[1] = LD128(brow + 2 * 2048 + c1);                                              \
    if (!(LASTF)) { STAGE2(1, nxt, ko); asm volatile("s_waitcnt vmcnt(3)" ::: "memory"); } \
    else          { asm volatile("s_waitcnt vmcnt(0)" ::: "memory"); }                \
    __builtin_amdgcn_s_barrier();                                                     \
    __builtin_amdgcn_s_setprio(1);                                                    \
    _Pragma("unroll") for (int mf = 0; mf < 2; ++mf) {                                \
      acc[mf][2] = mfma16(a[mf][0], b2[0], acc[mf][2]);                               \
      acc[mf][2] = mfma16(a[mf][1], b2[1], acc[mf][2]);                               \
    }                                                                                 \
    __builtin_amdgcn_s_setprio(0);                                                    \
    _Pragma("unroll") for (int mf = 0; mf < 2; ++mf) {                                \
      a[mf][0] = LD128(arow + (mf + 2) * 2048 + c0);                                  \
      a[mf][1] = LD128(arow + (mf + 2) * 2048 + c1);                                  \
    }                                                                                 \
    if (!(LASTF)) STAGE1(2, nxt, ko);                                                 \
    asm volatile("" ::: "memory");                                                    \
    __builtin_amdgcn_s_barrier();                                                     \
    __builtin_amdgcn_s_setprio(1);                                                    \
    _Pragma("unroll") for (int mf = 0; mf < 2; ++mf)                                  \
      _Pragma("unroll") for (int nf = 0; nf < 2; ++nf) {                              \
        acc[mf + 2][nf] = mfma16(a[mf][0], b01[nf][0], acc[mf + 2][nf]);              \
        acc[mf + 2][nf] = mfma16(a[mf][1], b01[nf][1], acc[mf + 2][nf]);              \
      }                                                                               \
    __builtin_amdgcn_s_setprio(0);                                                    \
    if (!(LASTF)) { STAGE1(3, nxt, ko); asm volatile("s_waitcnt vmcnt(2)" ::: "memory"); } \
    else          { asm volatile("" ::: "memory"); }                                  \
    __builtin_amdgcn_s_barrier();                                                     \
    __builtin_amdgcn_s_setprio(1);                                                    \
    _Pragma("unroll") for (int mf = 0; mf < 2; ++mf) {                                \
      acc[mf + 2][2] = mfma16(a[mf][0], b2[0], acc[mf + 2][2]);                       \
      acc[mf + 2][2] = mfma16(a[mf][1], b2[1], acc[mf + 2][2]);                       \
    }                                                                                 \
    __builtin_amdgcn_s_setprio(0);                                                    \
  }

#pragma unroll 1
  for (int kt = 0; kt < 11; ++kt) KBODY(kt, false);
  KBODY(11, true);
#undef KBODY
#undef STAGE2
#undef STAGE1
#undef LD128

  if constexpr (MODE == 0) {
    const int s = j0 / 768;
    const int jin0 = (j0 % 768) + wc * 48 + (l & 15);
    const int ntok0 = m0 + wr * 64 + ((l >> 4) << 2);
#pragma unroll
    for (int mf = 0; mf < 4; ++mf) {
      const int nt = ntok0 + mf * 16;
      const int bb = nt >> 10, nin = nt & 1023;
#pragma unroll
      for (int nf = 0; nf < 3; ++nf) {
        const int jj = jin0 + nf * 16;
        const int hh = jj / 96, dd = jj % 96;
        if (s == 2) {
          unsigned short* vp = o2 + (size_t)nt * 768 + jj;
#pragma unroll
          for (int rr = 0; rr < 4; ++rr) vp[rr * 768] = f2bf(acc[mf][nf][rr]);
        } else {
          unsigned short* base = (s == 0) ? o0 : o1;
          ushort4 pk;
          pk.x = f2bf(acc[mf][nf][0]); pk.y = f2bf(acc[mf][nf][1]);
          pk.z = f2bf(acc[mf][nf][2]); pk.w = f2bf(acc[mf][nf][3]);
          *(ushort4*)(base + ((size_t)((bb * 8 + hh) * 96 + dd)) * 1024 + nin) = pk;
        }
      }
    }
  } else {
    const int ntok0 = m0 + wr * 64 + ((l >> 4) << 2);
    const int col0 = j0 + wc * 48 + (l & 15);
#pragma unroll
    for (int mf = 0; mf < 4; ++mf)
#pragma unroll
      for (int nf = 0; nf < 3; ++nf) {
        unsigned short* yp = o0 + (size_t)(ntok0 + mf * 16) * 768 + col0 + nf * 16;
#pragma unroll
        for (int rr = 0; rr < 4; ++rr) yp[rr * 768] = f2bf(acc[mf][nf][rr]);
      }
  }
}

// ---------- A' = q^T k; scale 1/(|q||k|temp); softmax; write P^T ----------
// Double-buffered pipelined staging: issue next K-tile's loads BEFORE current
// MFMA phase; one vmcnt(0)+barrier per tile (T3-minimal 2-phase).
DEVI float ssq8(uint4 u) {
  unsigned a[4] = {u.x, u.y, u.z, u.w};
  float s = 0.f;
#pragma unroll
  for (int i = 0; i < 4; ++i) {
    float lo = __builtin_bit_cast(float, a[i] << 16);
    float hi = __builtin_bit_cast(float, a[i] & 0xFFFF0000u);
    s += lo * lo + hi * hi;
  }
  return s;
}

__global__ __launch_bounds__(256) void k_attn(const unsigned short* __restrict__ qT,
                                              const unsigned short* __restrict__ kT,
                                              const float* __restrict__ temp,
                                              unsigned short* __restrict__ PT) {
  __shared__ alignas(16) char lQK[2][24576];   // per buf: q [96][64] @0, k @12288 (swizzled)
  __shared__ float lA[96 * 96];
  __shared__ float lrq[96], lrk[96];
  const int bh = blockIdx.x, tid = threadIdx.x, lane = tid & 63, wid = tid >> 6;
  const float invt = 1.f / temp[bh & 7];
  const int wr = wid >> 1, wc = wid & 1;
  const unsigned short* qb = qT + (size_t)bh * 96 * 1024;
  const unsigned short* kb = kT + (size_t)bh * 96 * 1024;

  const unsigned short* srcp[6];
  int dsto[6];
#pragma unroll
  for (int i = 0; i < 6; ++i) {
    int cid = wid * 6 + i;          // 24 chunks: 12 q + 12 k
    bool isK = cid >= 12;
    int c = isK ? cid - 12 : cid;
    int p = c * 1024 + lane * 16;
    int r = p >> 7, cb = p & 127;
    int cbs = cb ^ ((r & 7) << 4);
    srcp[i] = (isK ? kb : qb) + (size_t)r * 1024 + (cbs >> 1);
    dsto[i] = (isK ? 12288 : 0) + c * 1024;
  }

  // issue tile 0 stage, then overlap norms compute with its latency
#pragma unroll
  for (int i = 0; i < 6; ++i) gload16(srcp[i], lQK[0] + dsto[i]);

  for (int row = wid; row < 192; row += 4) {
    const unsigned short* src = (row < 96) ? qb + (size_t)row * 1024
                                           : kb + (size_t)(row - 96) * 1024;
    const uint4* p = (const uint4*)src + lane * 2;
    float s = ssq8(p[0]) + ssq8(p[1]);
#pragma unroll
    for (int off = 32; off; off >>= 1) s += __shfl_xor(s, off, 64);
    if (lane == 0) {
      float r = 1.f / fmaxf(sqrtf(s), 1e-12f);
      if (row < 96) lrq[row] = r;
      else          lrk[row - 96] = r;
    }
  }

  f32x4 acc[3][3];
#pragma unroll
  for (int i = 0; i < 3; ++i)
#pragma unroll
    for (int j = 0; j < 3; ++j)
#pragma unroll
      for (int e = 0; e < 4; ++e) acc[i][j][e] = 0.f;

  asm volatile("s_waitcnt vmcnt(0)" ::: "memory");
  __builtin_amdgcn_s_barrier();

#pragma unroll 1
  for (int kt = 0; kt < 16; ++kt) {
    const char* bq = lQK[kt & 1];
    if (kt < 15) {
      char* nb = lQK[(kt + 1) & 1];
      const int ko = (kt + 1) * 64;
#pragma unroll
      for (int i = 0; i < 6; ++i) gload16(srcp[i] + ko, nb + dsto[i]);
    }
#pragma unroll
    for (int ks = 0; ks < 2; ++ks) {
      const int kb2 = ks * 64 + ((lane >> 4) << 4);
      bf16x8 af[3], bfv[3];
#pragma unroll
      for (int mb = 0; mb < 3; ++mb) af[mb] = frag_ld<128>(bq, wr * 48 + mb * 16 + (lane & 15), kb2);
#pragma unroll
      for (int nb2 = 0; nb2 < 3; ++nb2) bfv[nb2] = frag_ld<128>(bq + 12288, wc * 48 + nb2 * 16 + (lane & 15), kb2);
#pragma unroll
      for (int mb = 0; mb < 3; ++mb)
#pragma unroll
        for (int nb2 = 0; nb2 < 3; ++nb2) acc[mb][nb2] = mfma16(af[mb], bfv[nb2], acc[mb][nb2]);
    }
    asm volatile("s_waitcnt vmcnt(0)" ::: "memory");
    __builtin_amdgcn_s_barrier();
  }

  const int rb = wr * 48 + ((lane >> 4) << 2);
  const int eb = wc * 48 + (lane & 15);
#pragma unroll
  for (int mb = 0; mb < 3; ++mb)
#pragma unroll
    for (int nb = 0; nb < 3; ++nb) {
      int e = eb + nb * 16;
#pragma unroll
      for (int rr = 0; rr < 4; ++rr) {
        int d = rb + mb * 16 + rr;
        lA[d * 96 + e] = acc[mb][nb][rr] * lrq[d] * lrk[e] * invt;
      }
    }
  __syncthreads();
  for (int d = wid; d < 96; d += 4) {
    float v0 = lA[d * 96 + lane];
    float v1 = (lane < 32) ? lA[d * 96 + 64 + lane] : -3.0e38f;
    float mx = fmaxf(v0, v1);
#pragma unroll
    for (int off = 32; off; off >>= 1) mx = fmaxf(mx, __shfl_xor(mx, off, 64));
    float p0 = __expf(v0 - mx);
    float p1 = (lane < 32) ? __expf(v1 - mx) : 0.f;
    float ssum = p0 + p1;
#pragma unroll
    for (int off = 32; off; off >>= 1) ssum += __shfl_xor(ssum, off, 64);
    float rs = 1.f / ssum;
    PT[((size_t)bh * 96 + lane) * 96 + d] = f2bf(p0 * rs);
    if (lane < 32) PT[((size_t)bh * 96 + 64 + lane) * 96 + d] = f2bf(p1 * rs);
  }
}

// ---------- B_b[(h,e), c] pre-contraction: B_h = P_h^T @ W_h^T ----------
// Epilogue transposes through LDS -> fully coalesced 192B-row writes to B_all.
__global__ __launch_bounds__(256) void k_prep(const unsigned short* __restrict__ PT,
                                              const float* __restrict__ wproj,
                                              unsigned short* __restrict__ B_all) {
  __shared__ alignas(16) char pl[19968 + 39936];   // lPt [96][104] | lW [192][104]
  unsigned short* lPt = (unsigned short*)pl;
  unsigned short* lW  = (unsigned short*)(pl + 19968);
  unsigned short* tr  = lW;                        // aliased after MFMA ([192][100])
  const int blk = blockIdx.x;
  const int b = blk >> 5, h = (blk >> 2) & 7, cq = blk & 3;
  const int tid = threadIdx.x, l = tid & 63, wid = tid >> 6;
  const int wr = wid >> 1, wc = wid & 1;

  const unsigned short* pt = PT + (size_t)(b * 8 + h) * 96 * 96;
  for (int idx = tid; idx < 1152; idx += 256) {
    int r = idx / 12, ch = idx % 12;
    *(uint4*)(lPt + r * 104 + ch * 8) = *(const uint4*)(pt + r * 96 + ch * 8);
  }
  for (int idx = tid; idx < 4608; idx += 256) {
    int r = idx / 24, ch = idx % 24;
    float4 f = *(const float4*)(wproj + (size_t)(cq * 192 + r) * 768 + h * 96 + ch * 4);
    ushort4 o;
    o.x = f2bf(f.x); o.y = f2bf(f.y); o.z = f2bf(f.z); o.w = f2bf(f.w);
    *(ushort4*)(lW + r * 104 + ch * 4) = o;
  }
  __syncthreads();

  f32x4 acc[3][6];
#pragma unroll
  for (int i = 0; i < 3; ++i)
#pragma unroll
    for (int j = 0; j < 6; ++j)
#pragma unroll
      for (int e = 0; e < 4; ++e) acc[i][j][e] = 0.f;

#pragma unroll
  for (int ks = 0; ks < 3; ++ks) {
    const int kof = ks * 32 + ((l >> 4) << 3);
    bf16x8 af[3], bv[6];
#pragma unroll
    for (int mb = 0; mb < 3; ++mb)
      af[mb] = __builtin_bit_cast(bf16x8, *(const uint4*)(lPt + (wr * 48 + mb * 16 + (l & 15)) * 104 + kof));
#pragma unroll
    for (int nb = 0; nb < 6; ++nb)
      bv[nb] = __builtin_bit_cast(bf16x8, *(const uint4*)(lW + (wc * 96 + nb * 16 + (l & 15)) * 104 + kof));
#pragma unroll
    for (int mb = 0; mb < 3; ++mb)
#pragma unroll
      for (int nb = 0; nb < 6; ++nb) acc[mb][nb] = mfma16(af[mb], bv[nb], acc[mb][nb]);
  }

  __syncthreads();                 // all lW reads done; safe to alias as tr
  const int e0 = wr * 48 + ((l >> 4) << 2);
  const int cl0 = wc * 96 + (l & 15);
#pragma unroll
  for (int mb = 0; mb < 3; ++mb)
#pragma unroll
    for (int nb = 0; nb < 6; ++nb) {
      ushort4 pk;
      pk.x = f2bf(acc[mb][nb][0]); pk.y = f2bf(acc[mb][nb][1]);
      pk.z = f2bf(acc[mb][nb][2]); pk.w = f2bf(acc[mb][nb][3]);
      *(ushort4*)(tr + (cl0 + nb * 16) * 100 + e0 + mb * 16) = pk;
    }
  __syncthreads();
  // coalesced write-out: row c -> B_all[b][cq*192+c][h*96 .. +96], 192B per row
  for (int idx = tid; idx < 2304; idx += 256) {
    int r = idx / 12, ch = idx % 12;
    uint4 u = *(const uint4*)(tr + r * 100 + ch * 8);
    *(uint4*)(B_all + ((size_t)(b * 768) + cq * 192 + r) * 768 + h * 96 + ch * 8) = u;
  }
}

// ---------- final: y = yp(bf16) + 0.1*dwconv3x3(xb bf16); LayerNorm ----------
__global__ __launch_bounds__(256) void k_final(const unsigned short* __restrict__ yp,
                                               const unsigned short* __restrict__ xb16,
                                               const float* __restrict__ cw,
                                               const float* __restrict__ gamma,
                                               const float* __restrict__ beta,
                                               float* __restrict__ out) {
  const int wid = threadIdx.x >> 6, lane = threadIdx.x & 63;
  const int m = blockIdx.x * 4 + wid;           // token id
  const int bb = m >> 10, n = m & 1023, yy = n >> 5, xx = n & 31;
  const unsigned short* xb = xb16 + (size_t)bb * 1024 * 768;

  float yv[3][4];
#pragma unroll
  for (int g = 0; g < 3; ++g) {
    const int c = g * 256 + lane * 4;
    float w36[36];
    const float4* wp = (const float4*)(cw + (size_t)c * 9);
#pragma unroll
    for (int i = 0; i < 9; ++i) *(float4*)(w36 + i * 4) = wp[i];

    float a0 = 0.f, a1 = 0.f, a2 = 0.f, a3 = 0.f;
#pragma unroll
    for (int dy = -1; dy <= 1; ++dy) {
      int ny = yy + dy;
      if ((unsigned)ny < 32u) {
#pragma unroll
        for (int dx = -1; dx <= 1; ++dx) {
          int nx = xx + dx;
          if ((unsigned)nx < 32u) {
            ushort4 v = *(const ushort4*)(xb + (size_t)(ny * 32 + nx) * 768 + c);
            const int j = (dy + 1) * 3 + (dx + 1);
            a0 += w36[0 * 9 + j] * bf2f(v.x);
            a1 += w36[1 * 9 + j] * bf2f(v.y);
            a2 += w36[2 * 9 + j] * bf2f(v.z);
            a3 += w36[3 * 9 + j] * bf2f(v.w);
          }
        }
      }
    }
    ushort4 f = *(const ushort4*)(yp + (size_t)m * 768 + c);
    yv[g][0] = bf2f(f.x) + 0.1f * a0;
    yv[g][1] = bf2f(f.y) + 0.1f * a1;
    yv[g][2] = bf2f(f.z) + 0.1f * a2;
    yv[g][3] = bf2f(f.w) + 0.1f * a3;
  }

  float s1 = 0.f, s2 = 0.f;
#pragma unroll
  for (int g = 0; g < 3; ++g)
#pragma unroll
    for (int e = 0; e < 4; ++e) { s1 += yv[g][e]; s2 += yv[g][e] * yv[g][e]; }
#pragma unroll
  for (int off = 32; off; off >>= 1) {
    s1 += __shfl_xor(s1, off, 64);
    s2 += __shfl_xor(s2, off, 64);
  }
  const float mu = s1 * (1.f / 768.f);
  const float var = s2 * (1.f / 768.f) - mu * mu;
  const float rs = rsqrtf(var + 1e-5f);

#pragma unroll
  for (int g = 0; g < 3; ++g) {
    const int c = g * 256 + lane * 4;
    float4 gm = *(const float4*)(gamma + c);
    float4 bt = *(const float4*)(beta + c);
    float4 o;
    o.x = (yv[g][0] - mu) * rs * gm.x + bt.x;
    o.y = (yv[g][1] - mu) * rs * gm.y + bt.y;
    o.z = (yv[g][2] - mu) * rs * gm.z + bt.z;
    o.w = (yv[g][3] - mu) * rs * gm.w + bt.w;
    *(float4*)(out + (size_t)m * 768 + c) = o;
  }
}

// ---------- host ----------
extern "C" void kernel_launch(void* const* d_in, const int* in_sizes, int n_in,
                              void* d_out, int out_size, void* d_ws, size_t ws_size,
                              hipStream_t stream) {
  const float* x     = (const float*)d_in[0];
  const float* wqkv  = (const float*)d_in[1];
  const float* wproj = (const float*)d_in[2];
  const float* temp  = (const float*)d_in[3];
  const float* cw    = (const float*)d_in[4];
  const float* gamma = (const float*)d_in[5];
  const float* beta  = (const float*)d_in[6];
  float* out = (float*)d_out;
  char* ws = (char*)d_ws;

  // workspace layout (~107 MiB; aliased regions are stream-ordered dead)
  unsigned short* xb    = (unsigned short*)(ws);               // 25165824 B (x bf16; live to k_final)
  unsigned short* wqb   = (unsigned short*)(ws + 25165824);    // 3538944 (dead after gemm0)
  unsigned short* qT    = (unsigned short*)(ws + 28704768);    // 25165824 (dead after attn)
  unsigned short* yp    = qT;                                  //   alias
  unsigned short* kT    = (unsigned short*)(ws + 53870592);    // 25165824 (dead after attn)
  unsigned short* B_all = kT;                                  //   alias: 16*768*768*2 = 18874368
  unsigned short* vP    = (unsigned short*)(ws + 79036416);    // 25165824
  unsigned short* PT    = (unsigned short*)(ws + 104202240);   // 2359296

  k_cvt2<<<dim3(2048), dim3(256), 0, stream>>>(x, xb, 16384 * 768 / 4,
                                               wqkv, wqb, 2304 * 768 / 4);
  k_gemm<0><<<dim3(1536), dim3(512), 0, stream>>>(xb, wqb, qT, kT, vP);
  k_attn<<<dim3(128), dim3(256), 0, stream>>>(qT, kT, temp, PT);
  k_prep<<<dim3(512), dim3(256), 0, stream>>>(PT, wproj, B_all);
  k_gemm<1><<<dim3(512), dim3(512), 0, stream>>>(vP, B_all, yp, nullptr, nullptr);
  k_final<<<dim3(4096), dim3(256), 0, stream>>>(yp, xb, cw, gamma, beta, out);
}